// Round 6
// baseline (460.746 us; speedup 1.0000x reference)
//
#include <hip/hip_runtime.h>
#include <hip/hip_bf16.h>

// LiteMSA pipeline, MI355X gfx950.
// B=16, Cin=256, Cqkv=768, H=W=64 (P=4096), heads=64 (24 ch: q8,k8,v8),
// out 512 ch -> proj 256 ch + BN. Output y fp32.
//
// GEMM1 (v6): pre-convert w_qkv and x to bf16 hi/lo ONCE (conv_w, conv_x),
// swizzled (16B slot ^= (row>>1)&3 per 64B window); gemm_q (q rows, 3-term
// split hh+lh+hl, 64KB LDS) and gemm_kv (k/v rows, 1-term, 32KB LDS, 4
// blocks/CU) stage via global_load_lds w=16, double-buffered with COUNTED
// vmcnt (8|4) + raw s_barrier pair per K-step. XCD-contiguous swizzle.
// qfix (v6): detection moved into gemm_q epilogue (sparse worklist via
// atomicAdd; ~4k entries) -> qfix2 does one wave per entry in fp64.
// No more 67MB qplane scan.
//
// ws (256 MiB):
//   qkv_bf [0,96M)    bf16 768ch
//   qplane [96M,160M) fp32 256ch (q of heads 0-31)
//   agg_bf [160M,256M) bf16 768ch; ALIASED before dwpw by:
//     XTh [+0,32M) XTl [+32M,64M)  x^T bf16 hi/lo [b][4096][256] swizzled
//     Awh/Awl [+64M, +64.75M)      w_qkv bf16 hi/lo [768 virt][256] swizzled
// d_out: kvbuf 288K scratch at head; qmeta (cnt + worklist) at +512K
// (consumed by qfix2 before kv/attn run; gemm_proj overwrites all).

#define NB 16
#define CQKV 768
#define P4096 4096
#define QFIX_CAP (1u << 21)

typedef __bf16 bf16x8 __attribute__((ext_vector_type(8)));
typedef float f32x4 __attribute__((ext_vector_type(4)));

#define MFMA_BF16 __builtin_amdgcn_mfma_f32_16x16x32_bf16

__device__ __forceinline__ ushort f2bf(float f) {
    union { float f; unsigned int u; } x; x.f = f;
    unsigned int u = x.u;
    unsigned int r = (u + 0x7FFFu + ((u >> 16) & 1u)) >> 16;
    return (ushort)r;
}
__device__ __forceinline__ float bf2f(ushort u) {
    union { unsigned int u; float f; } x; x.u = ((unsigned int)u) << 16;
    return x.f;
}
__device__ __forceinline__ unsigned int pk2bf(float x, float y) {
    __hip_bfloat162 h = __float22bfloat162_rn(make_float2(x, y));  // v_cvt_pk_bf16_f32 (RNE)
    union { __hip_bfloat162 b; unsigned int u; } c; c.b = h; return c.u;
}
// 8 fp32 -> bf16 hi (one b128 LDS write)
__device__ __forceinline__ void stage_hi8(const float* v, ushort* dh) {
    union { unsigned int u[4]; uint4 q; } H;
    #pragma unroll
    for (int i = 0; i < 4; i++) H.u[i] = pk2bf(v[2 * i], v[2 * i + 1]);
    *(uint4*)dh = H.q;
}

__device__ __forceinline__ void gload16(void* lds, const void* g) {
    __builtin_amdgcn_global_load_lds(
        (const __attribute__((address_space(1))) void*)g,
        (__attribute__((address_space(3))) void*)lds, 16, 0, 0);
}

// ---------------- conv_w: w_qkv -> virt-row-ordered, swizzled bf16 hi/lo ----------------
// virt rows: 0..255 q (phys=(v>>3)*24+v&7), 256..767 kv (phys=(v2>>4)*24+8+v2&15).
__global__ __launch_bounds__(128) void conv_w(
    const float* __restrict__ W, ushort* __restrict__ Ah, ushort* __restrict__ Al)
{
    const int rv = blockIdx.x;     // 0..767
    const int t  = threadIdx.x;    // 0..127 -> c pair
    int phys;
    if (rv < 256) phys = (rv >> 3) * 24 + (rv & 7);
    else { int r2 = rv - 256; phys = (r2 >> 4) * 24 + 8 + (r2 & 15); }
    int c = t * 2;
    float w0 = W[(size_t)phys * 256 + c];
    float w1 = W[(size_t)phys * 256 + c + 1];
    unsigned int h = pk2bf(w0, w1);
    float f0 = __uint_as_float(h << 16);
    float f1 = __uint_as_float(h & 0xffff0000u);
    unsigned int l = pk2bf(w0 - f0, w1 - f1);
    int sl = ((c >> 3) & 3) ^ ((rv >> 1) & 3);
    int idx = (c & ~31) + sl * 8 + (c & 7);
    *(unsigned int*)&Ah[(size_t)rv * 256 + idx] = h;
    *(unsigned int*)&Al[(size_t)rv * 256 + idx] = l;
}

// ---------------- conv_x: x [b][256][4096] f32 -> XT hi/lo [b][4096][256] bf16, swizzled ----------------
__global__ __launch_bounds__(256) void conv_x(
    const float* __restrict__ X, ushort* __restrict__ XTh, ushort* __restrict__ XTl)
{
    const int pt = blockIdx.x;        // 0..63
    const int ct = blockIdx.y;        // 0..3
    const int b  = blockIdx.z;
    const int t  = threadIdx.x;
    const int p0 = pt * 64, c0 = ct * 64;

    __shared__ float tile[64][65];

    {
        int cr = t >> 2, pc = (t & 3) * 16;
        const float* xr = X + ((size_t)b * 256 + c0 + cr) * P4096 + p0 + pc;
        float4 v0 = *(const float4*)xr;
        float4 v1 = *(const float4*)(xr + 4);
        float4 v2 = *(const float4*)(xr + 8);
        float4 v3 = *(const float4*)(xr + 12);
        float* d = &tile[cr][pc];
        d[0]=v0.x; d[1]=v0.y; d[2]=v0.z; d[3]=v0.w;
        d[4]=v1.x; d[5]=v1.y; d[6]=v1.z; d[7]=v1.w;
        d[8]=v2.x; d[9]=v2.y; d[10]=v2.z; d[11]=v2.w;
        d[12]=v3.x; d[13]=v3.y; d[14]=v3.z; d[15]=v3.w;
    }
    __syncthreads();

    #pragma unroll
    for (int pass = 0; pass < 2; pass++) {
        int tp = t >> 2;
        int cc = (t & 3) + pass * 4;      // 0..7 chunk of 8 c
        int p  = p0 + tp;
        float v[8];
        #pragma unroll
        for (int j = 0; j < 8; j++) v[j] = tile[cc * 8 + j][tp];
        union { unsigned int u[4]; uint4 q; } H, L;
        #pragma unroll
        for (int i = 0; i < 4; i++) {
            unsigned int h = pk2bf(v[2 * i], v[2 * i + 1]);
            H.u[i] = h;
            float f0 = __uint_as_float(h << 16);
            float f1 = __uint_as_float(h & 0xffff0000u);
            L.u[i] = pk2bf(v[2 * i] - f0, v[2 * i + 1] - f1);
        }
        int c = c0 + cc * 8;
        int sl = ((c >> 3) & 3) ^ ((p >> 1) & 3);
        size_t idx = ((size_t)b * P4096 + p) * 256 + (c & ~31) + sl * 8;
        *(uint4*)&XTh[idx] = H.q;
        *(uint4*)&XTl[idx] = L.q;
    }
}

// ---------------- zero worklist counter ----------------
__global__ void zero_cnt(unsigned int* qmeta) { if (threadIdx.x == 0) qmeta[0] = 0; }

// ---------------- gemm_q: q rows (virt 0..255), 3-term split + qfix detection ----------------
// 128x128 tile, BK=32, 4 waves 2x2, acc 4x4. Double-buffered, counted vmcnt(8).
// Grid 1024, XCD swizzle lg=(hw&7)*128+(hw>>3).
__global__ __launch_bounds__(256, 2) void gemm_q(
    const ushort* __restrict__ Ah, const ushort* __restrict__ Al,
    const ushort* __restrict__ Bh, const ushort* __restrict__ Bl,
    ushort* __restrict__ Cbf, float* __restrict__ qplane,
    unsigned int* __restrict__ qmeta)
{
    const int hw = blockIdx.x;                 // 0..1023
    const int lg = (hw & 7) * 128 + (hw >> 3);
    const int mt = lg & 1;
    const int rem = lg >> 1;                   // 0..511
    const int n0 = (rem & 31) * 128;
    const int b  = rem >> 5;
    const int t  = threadIdx.x;
    const int wave = t >> 6, lane = t & 63, quad = lane >> 4, l15 = lane & 15;
    const int wr = wave >> 1, wc = wave & 1;
    const int M0 = mt * 128;

    __shared__ __align__(16) ushort AsH[2][4096];
    __shared__ __align__(16) ushort AsL[2][4096];
    __shared__ __align__(16) ushort BsH[2][4096];
    __shared__ __align__(16) ushort BsL[2][4096];

    int aoff[4], boff[4];
    #pragma unroll
    for (int i = 0; i < 4; i++) {
        int ra = wr * 64 + i * 16 + l15;
        aoff[i] = ra * 64 + ((quad ^ ((ra >> 1) & 3)) << 4);
        int rb = wc * 64 + i * 16 + l15;
        boff[i] = rb * 64 + ((quad ^ ((rb >> 1) & 3)) << 4);
    }

    const int srow = t >> 2;               // 0..63
    const int schunk = (t & 3) * 8;
    const size_t abase = (size_t)(M0 + srow) * 256 + schunk;
    const size_t bbase = ((size_t)b * P4096 + n0 + srow) * 256 + schunk;
    const int ldsoff = wave * 1024;        // bytes; +i*4096

    f32x4 acc[4][4];
    #pragma unroll
    for (int mi = 0; mi < 4; mi++)
        #pragma unroll
        for (int nj = 0; nj < 4; nj++)
            #pragma unroll
            for (int r = 0; r < 4; r++) acc[mi][nj][r] = 0.0f;

    auto stageQ = [&](int d, int kw) {
        #pragma unroll
        for (int i = 0; i < 2; i++) {
            int lo = ldsoff + i * 4096;
            size_t so = (size_t)(i * 64) * 256 + (size_t)kw * 32;
            gload16((char*)AsH[d] + lo, Ah + abase + so);
            gload16((char*)AsL[d] + lo, Al + abase + so);
            gload16((char*)BsH[d] + lo, Bh + bbase + so);
            gload16((char*)BsL[d] + lo, Bl + bbase + so);
        }
    };
    stageQ(0, 0);
    for (int kw = 0; kw < 8; kw++) {
        int cur = kw & 1;
        if (kw < 7) {
            stageQ(cur ^ 1, kw + 1);
            asm volatile("s_waitcnt vmcnt(8)" ::: "memory");
        } else {
            asm volatile("s_waitcnt vmcnt(0)" ::: "memory");
        }
        __builtin_amdgcn_s_barrier();
        bf16x8 ah[4], al[4];
        #pragma unroll
        for (int mi = 0; mi < 4; mi++) {
            ah[mi] = *(const bf16x8*)((const char*)AsH[cur] + aoff[mi]);
            al[mi] = *(const bf16x8*)((const char*)AsL[cur] + aoff[mi]);
        }
        #pragma unroll
        for (int nj = 0; nj < 4; nj++) {
            bf16x8 bh = *(const bf16x8*)((const char*)BsH[cur] + boff[nj]);
            bf16x8 bl = *(const bf16x8*)((const char*)BsL[cur] + boff[nj]);
            #pragma unroll
            for (int mi = 0; mi < 4; mi++) {
                acc[mi][nj] = MFMA_BF16(ah[mi], bh, acc[mi][nj], 0, 0, 0);
                acc[mi][nj] = MFMA_BF16(al[mi], bh, acc[mi][nj], 0, 0, 0);
                acc[mi][nj] = MFMA_BF16(ah[mi], bl, acc[mi][nj], 0, 0, 0);
            }
        }
        __builtin_amdgcn_s_barrier();   // reads of buf[cur] done before next overwrite
    }

    unsigned int* qlist = qmeta + 16;
    #pragma unroll
    for (int mi = 0; mi < 4; mi++)
        #pragma unroll
        for (int nj = 0; nj < 4; nj++)
            #pragma unroll
            for (int r = 0; r < 4; r++) {
                int rv = M0 + wr * 64 + mi * 16 + quad * 4 + r;
                int rp = (rv >> 3) * 24 + (rv & 7);
                int col = n0 + wc * 64 + nj * 16 + l15;
                float v = acc[mi][nj][r];
                Cbf[((size_t)b * CQKV + rp) * P4096 + col] = f2bf(v);
                qplane[((size_t)b * 256 + rv) * P4096 + col] = v;
                if (fabsf(v) < 1e-4f) {   // sparse qfix worklist (~2.5e-4 hit rate)
                    unsigned int idx = atomicAdd(qmeta, 1u);
                    if (idx < QFIX_CAP)
                        qlist[idx] = (unsigned int)(((b * 256 + rv) << 12) | col);
                }
            }
}

// ---------------- gemm_kv: k/v rows (virt2 0..511), 1-term, 32KB LDS ----------------
// Grid 2048, XCD swizzle lg=(hw&7)*256+(hw>>3). 4 blocks/CU.
__global__ __launch_bounds__(256, 4) void gemm_kv(
    const ushort* __restrict__ Ah, const ushort* __restrict__ Bh,
    ushort* __restrict__ Cbf)
{
    const int hw = blockIdx.x;                 // 0..2047
    const int lg = (hw & 7) * 256 + (hw >> 3);
    const int mt = lg & 3;
    const int rem = lg >> 2;                   // 0..511
    const int n0 = (rem & 31) * 128;
    const int b  = rem >> 5;
    const int t  = threadIdx.x;
    const int wave = t >> 6, lane = t & 63, quad = lane >> 4, l15 = lane & 15;
    const int wr = wave >> 1, wc = wave & 1;
    const int M0 = mt * 128;                   // virt2 base

    __shared__ __align__(16) ushort As[2][4096];
    __shared__ __align__(16) ushort Bs[2][4096];

    int aoff[4], boff[4];
    #pragma unroll
    for (int i = 0; i < 4; i++) {
        int ra = wr * 64 + i * 16 + l15;
        aoff[i] = ra * 64 + ((quad ^ ((ra >> 1) & 3)) << 4);
        int rb = wc * 64 + i * 16 + l15;
        boff[i] = rb * 64 + ((quad ^ ((rb >> 1) & 3)) << 4);
    }

    const int srow = t >> 2;
    const int schunk = (t & 3) * 8;
    const size_t abase = (size_t)(256 + M0 + srow) * 256 + schunk;  // virt rows 256..767
    const size_t bbase = ((size_t)b * P4096 + n0 + srow) * 256 + schunk;
    const int ldsoff = wave * 1024;

    f32x4 acc[4][4];
    #pragma unroll
    for (int mi = 0; mi < 4; mi++)
        #pragma unroll
        for (int nj = 0; nj < 4; nj++)
            #pragma unroll
            for (int r = 0; r < 4; r++) acc[mi][nj][r] = 0.0f;

    auto stageKV = [&](int d, int kw) {
        #pragma unroll
        for (int i = 0; i < 2; i++) {
            int lo = ldsoff + i * 4096;
            size_t so = (size_t)(i * 64) * 256 + (size_t)kw * 32;
            gload16((char*)As[d] + lo, Ah + abase + so);
            gload16((char*)Bs[d] + lo, Bh + bbase + so);
        }
    };
    stageKV(0, 0);
    for (int kw = 0; kw < 8; kw++) {
        int cur = kw & 1;
        if (kw < 7) {
            stageKV(cur ^ 1, kw + 1);
            asm volatile("s_waitcnt vmcnt(4)" ::: "memory");
        } else {
            asm volatile("s_waitcnt vmcnt(0)" ::: "memory");
        }
        __builtin_amdgcn_s_barrier();
        bf16x8 ah[4];
        #pragma unroll
        for (int mi = 0; mi < 4; mi++)
            ah[mi] = *(const bf16x8*)((const char*)As[cur] + aoff[mi]);
        #pragma unroll
        for (int nj = 0; nj < 4; nj++) {
            bf16x8 bh = *(const bf16x8*)((const char*)Bs[cur] + boff[nj]);
            #pragma unroll
            for (int mi = 0; mi < 4; mi++)
                acc[mi][nj] = MFMA_BF16(ah[mi], bh, acc[mi][nj], 0, 0, 0);
        }
        __builtin_amdgcn_s_barrier();
    }
    #pragma unroll
    for (int mi = 0; mi < 4; mi++)
        #pragma unroll
        for (int nj = 0; nj < 4; nj++)
            #pragma unroll
            for (int r = 0; r < 4; r++) {
                int rv2 = M0 + wr * 64 + mi * 16 + quad * 4 + r;
                int rp = (rv2 >> 4) * 24 + 8 + (rv2 & 15);
                int col = n0 + wc * 64 + nj * 16 + l15;
                Cbf[((size_t)b * CQKV + rp) * P4096 + col] = f2bf(acc[mi][nj][r]);
            }
}

// ---------------- qfix2: sparse fp64 recompute, one wave per worklist entry ----------------
__global__ __launch_bounds__(256) void qfix2_kernel(
    float* __restrict__ qplane, const float* __restrict__ w_qkv,
    const float* __restrict__ x, const unsigned int* __restrict__ qmeta)
{
    unsigned int n = qmeta[0];
    if (n > QFIX_CAP) n = QFIX_CAP;
    const unsigned int* list = qmeta + 16;
    const int wave = threadIdx.x >> 6, lane = threadIdx.x & 63;
    for (unsigned int e = blockIdx.x * 4 + wave; e < n; e += gridDim.x * 4) {
        unsigned int i = list[e];
        int p   = (int)(i & 4095);
        int qch = (int)((i >> 12) & 255);
        int b   = (int)(i >> 20);
        int row = (qch >> 3) * 24 + (qch & 7);
        const float* wr = w_qkv + (size_t)row * 256;
        const float* xr = x + (size_t)b * 256 * P4096 + p;
        double s = 0.0;
        #pragma unroll
        for (int j = 0; j < 4; j++) {
            int c = lane * 4 + j;
            s += (double)wr[c] * (double)xr[(size_t)c * P4096];
        }
        #pragma unroll
        for (int off = 32; off > 0; off >>= 1) s += __shfl_xor(s, off, 64);
        if (lane == 0)
            qplane[((size_t)(b * 256 + qch)) * P4096 + p] = (float)s;
    }
}

// ---------------- dw 3x3 + grouped pw (bf16; feeds only heads 32-63) ----------------
__global__ __launch_bounds__(512, 8) void dwpw_kernel(
    const ushort* __restrict__ qkv, const float* __restrict__ wdw,
    const float* __restrict__ wpw, ushort* __restrict__ agg)
{
    const int rt = blockIdx.x;    // 0..3 (16 output rows each)
    const int g  = blockIdx.y;    // 0..95
    const int b  = blockIdx.z;
    const int t  = threadIdx.x;   // 0..511
    const int r0 = rt * 16;
    const int cg = g * 8;

    __shared__ __align__(16) ushort tile[8][18][80];   // 23040 B

    const ushort* src = qkv + ((size_t)(b * CQKV + cg)) * P4096;

    if (t < 288) {
        int ch = t / 36;
        int rr = (t % 36) >> 1;
        int side = t & 1;
        *(uint4*)&tile[ch][rr][side * 72] = make_uint4(0, 0, 0, 0);
    }
    #pragma unroll
    for (int i = 0; i < 3; i++) {
        int id = t + i * 512;
        if (id < 1152) {
            int ch  = id / 144;
            int rem = id - ch * 144;
            int rr  = rem >> 3;
            int oct = (rem & 7) * 8;
            int grow = r0 - 1 + rr;
            uint4 v = make_uint4(0, 0, 0, 0);
            if (grow >= 0 && grow < 64)
                v = *(const uint4*)(src + (size_t)ch * P4096 + (size_t)grow * 64 + oct);
            *(uint4*)&tile[ch][rr][8 + oct] = v;
        }
    }
    __syncthreads();

    const int kc  = t & 31;        // col pair: cols 2kc, 2kc+1
    const int row = t >> 5;        // 0..15
    const float* wdwg = wdw + (size_t)cg * 9;   // block-uniform -> s_load
    const float* wpwg = wpw + (size_t)cg * 8;

    float acc0[8], acc1[8];
    #pragma unroll
    for (int oi = 0; oi < 8; oi++) { acc0[oi] = 0.0f; acc1[oi] = 0.0f; }

    #pragma unroll
    for (int c = 0; c < 8; c++) {
        float dv0 = 0.0f, dv1 = 0.0f;
        #pragma unroll
        for (int dy = 0; dy < 3; dy++) {
            const ushort* rp = &tile[c][row + dy][2 * kc + 4];
            unsigned int u1 = *(const unsigned int*)(rp + 2);
            unsigned int u2 = *(const unsigned int*)(rp + 4);
            unsigned int u3 = *(const unsigned int*)(rp + 6);
            float xm1 = __uint_as_float(u1 & 0xffff0000u);
            float x0  = __uint_as_float(u2 << 16);
            float x1  = __uint_as_float(u2 & 0xffff0000u);
            float x2  = __uint_as_float(u3 << 16);
            float w0 = wdwg[c * 9 + dy * 3 + 0];
            float w1 = wdwg[c * 9 + dy * 3 + 1];
            float w2 = wdwg[c * 9 + dy * 3 + 2];
            dv0 = fmaf(w0, xm1, dv0); dv0 = fmaf(w1, x0, dv0); dv0 = fmaf(w2, x1, dv0);
            dv1 = fmaf(w0, x0,  dv1); dv1 = fmaf(w1, x1, dv1); dv1 = fmaf(w2, x2, dv1);
        }
        #pragma unroll
        for (int oi = 0; oi < 8; oi++) {
            float w = wpwg[oi * 8 + c];
            acc0[oi] = fmaf(w, dv0, acc0[oi]);
            acc1[oi] = fmaf(w, dv1, acc1[oi]);
        }
    }

    size_t obase = ((size_t)(b * CQKV + cg)) * P4096 + (size_t)(r0 + row) * 64 + 2 * kc;
    #pragma unroll
    for (int oi = 0; oi < 8; oi++) {
        unsigned int u = (unsigned int)f2bf(acc0[oi]) |
                         ((unsigned int)f2bf(acc1[oi]) << 16);
        *(unsigned int*)&agg[obase + (size_t)oi * P4096] = u;
    }
}

// ---------------- kv[b,h,d,e] = sum_p relu(k_d)*v_e  (v_8 = 1) ----------------
__global__ __launch_bounds__(256) void kv_kernel(
    const ushort* __restrict__ qkv, const ushort* __restrict__ agg,
    float* __restrict__ kv)
{
    const int h = blockIdx.x, b = blockIdx.y, t = threadIdx.x;
    const ushort* src = (h < 32)
        ? qkv + ((size_t)(b * CQKV + h * 24)) * P4096
        : agg + ((size_t)(b * CQKV + (h - 32) * 24)) * P4096;

    float acc[72];
    #pragma unroll
    for (int i = 0; i < 72; i++) acc[i] = 0.0f;

    for (int pi = 0; pi < 16; pi++) {
        int p = t + pi * 256;
        float kvv[8], vv[8];
        #pragma unroll
        for (int d = 0; d < 8; d++) {
            float xk = bf2f(src[(size_t)(8 + d) * P4096 + p]);
            kvv[d] = xk > 0.0f ? xk : 0.0f;
        }
        #pragma unroll
        for (int e = 0; e < 8; e++) vv[e] = bf2f(src[(size_t)(16 + e) * P4096 + p]);
        #pragma unroll
        for (int d = 0; d < 8; d++) {
            #pragma unroll
            for (int e = 0; e < 8; e++) acc[d * 9 + e] += kvv[d] * vv[e];
            acc[d * 9 + 8] += kvv[d];
        }
    }

    #pragma unroll
    for (int i = 0; i < 72; i++) {
        float v = acc[i];
        #pragma unroll
        for (int off = 32; off > 0; off >>= 1) v += __shfl_xor(v, off, 64);
        acc[i] = v;
    }
    __shared__ float part[4][72];
    int wave = t >> 6, lane = t & 63;
    if (lane == 0) {
        #pragma unroll
        for (int i = 0; i < 72; i++) part[wave][i] = acc[i];
    }
    __syncthreads();
    if (t < 72)
        kv[((size_t)b * 64 + h) * 72 + t] = part[0][t] + part[1][t] + part[2][t] + part[3][t];
}

// ---------------- attn: out = (q.kv)_e / ((q.kv)_8 + 1e-15) ----------------
__global__ __launch_bounds__(256) void attn_out_kernel(
    const float* __restrict__ qplane, ushort* __restrict__ agg,
    const float* __restrict__ kv)
{
    const int pt = blockIdx.x, h = blockIdx.y, b = blockIdx.z, t = threadIdx.x;
    __shared__ float kvs[72];
    if (t < 72) kvs[t] = kv[((size_t)b * 64 + h) * 72 + t];
    __syncthreads();

    const bool lohead = (h < 32);
    const float* srcf = lohead
        ? qplane + ((size_t)(b * 256 + h * 8)) * P4096 : nullptr;
    const ushort* srcb = lohead ? nullptr
        : agg + ((size_t)(b * CQKV + (h - 32) * 24)) * P4096;

    int p = pt * 256 + t;
    float num[8]; float den = 0.0f;
    #pragma unroll
    for (int e = 0; e < 8; e++) num[e] = 0.0f;
    #pragma unroll
    for (int d = 0; d < 8; d++) {
        float q = lohead ? srcf[(size_t)d * P4096 + p]
                         : bf2f(srcb[(size_t)d * P4096 + p]);
        q = q > 0.0f ? q : 0.0f;
        #pragma unroll
        for (int e = 0; e < 8; e++) num[e] += q * kvs[d * 9 + e];
        den += q * kvs[d * 9 + 8];
    }
    float rd = 1.0f / (den + 1e-15f);
    ushort* dst = agg + ((size_t)(b * CQKV + (h / 2) * 24 + 8 + (h % 2) * 8)) * P4096 + p;
    #pragma unroll
    for (int e = 0; e < 8; e++)
        dst[(size_t)e * P4096] = f2bf(num[e] * rd);
}

// ---------------- GEMM3: y = W_proj(256x512) @ out[b](512x4096), bf16, BN ----------------
__global__ __launch_bounds__(256) void gemm_proj(
    const float* __restrict__ A,       // 256 x 512 fp32
    const ushort* __restrict__ Bagg,   // out in agg's k/v slots, map(k)=(k/16)*24+8+(k%16)
    float* __restrict__ Y,
    const float* __restrict__ bn_g, const float* __restrict__ bn_b,
    const float* __restrict__ bn_m, const float* __restrict__ bn_v)
{
    const int n0 = blockIdx.x * 64;
    const int m0 = blockIdx.y * 64;
    const int b  = blockIdx.z;
    const int t  = threadIdx.x;
    const int wave = t >> 6, lane = t & 63, quad = lane >> 4, l15 = lane & 15;

    __shared__ __align__(16) ushort As[64][40];
    __shared__ __align__(16) ushort Bs[64][40];

    f32x4 acc[4];
    #pragma unroll
    for (int nt = 0; nt < 4; nt++)
        #pragma unroll
        for (int r = 0; r < 4; r++) acc[nt][r] = 0.0f;

    const int am = t >> 2, ak = (t & 3) * 8;
    const int bn = t & 63, kg = (t >> 6) * 8;

    for (int k0 = 0; k0 < 512; k0 += 32) {
        float av[8];
        *(float4*)&av[0] = *(const float4*)(A + (size_t)(m0 + am) * 512 + k0 + ak);
        *(float4*)&av[4] = *(const float4*)(A + (size_t)(m0 + am) * 512 + k0 + ak + 4);
        ushort bu[8];
        #pragma unroll
        for (int i = 0; i < 8; i++) {
            int kk = k0 + kg + i;
            int amch = (kk >> 4) * 24 + 8 + (kk & 15);
            bu[i] = Bagg[((size_t)b * CQKV + amch) * P4096 + n0 + bn];
        }

        __syncthreads();
        stage_hi8(av, &As[am][ak]);
        {
            union { ushort us[8]; uint4 q; } Bp;
            #pragma unroll
            for (int i = 0; i < 8; i++) Bp.us[i] = bu[i];
            *(uint4*)&Bs[bn][kg] = Bp.q;
        }
        __syncthreads();

        bf16x8 af = *(const bf16x8*)&As[wave * 16 + l15][quad * 8];
        #pragma unroll
        for (int nt = 0; nt < 4; nt++) {
            bf16x8 bf = *(const bf16x8*)&Bs[nt * 16 + l15][quad * 8];
            acc[nt] = MFMA_BF16(af, bf, acc[nt], 0, 0, 0);
        }
    }

    #pragma unroll
    for (int nt = 0; nt < 4; nt++) {
        #pragma unroll
        for (int r = 0; r < 4; r++) {
            int row = m0 + wave * 16 + quad * 4 + r;
            int col = n0 + nt * 16 + l15;
            float inv = bn_g[row] / sqrtf(bn_v[row] + 1e-5f);
            float v = acc[nt][r] * inv + (bn_b[row] - bn_m[row] * inv);
            Y[((size_t)b * 256 + row) * P4096 + col] = v;
        }
    }
}

// ---------------- launch ----------------
extern "C" void kernel_launch(void* const* d_in, const int* in_sizes, int n_in,
                              void* d_out, int out_size, void* d_ws, size_t ws_size,
                              hipStream_t stream) {
    const float* x      = (const float*)d_in[0];
    const float* w_qkv  = (const float*)d_in[1];
    const float* w_dw   = (const float*)d_in[2];
    const float* w_pw   = (const float*)d_in[3];
    const float* w_proj = (const float*)d_in[4];
    const float* bn_g   = (const float*)d_in[5];
    const float* bn_b   = (const float*)d_in[6];
    const float* bn_m   = (const float*)d_in[7];
    const float* bn_v   = (const float*)d_in[8];
    float* y = (float*)d_out;

    char* ws = (char*)d_ws;
    ushort* qkv_bf = (ushort*)(ws);                  // 96 MiB: bf16 768ch
    float*  qplane = (float*) (ws + 100663296);      // 64 MiB: fp32 q (heads 0-31)
    ushort* agg_bf = (ushort*)(ws + 167772160);      // 96 MiB: agg; k/v slots reused for out
    // aliases inside agg region, dead once dwpw runs:
    ushort* XTh = (ushort*)(ws + 167772160);                       // 32 MiB
    ushort* XTl = (ushort*)(ws + 167772160 + 33554432);            // 32 MiB
    ushort* Awh = (ushort*)(ws + 167772160 + 67108864);            // 384 KiB
    ushort* Awl = (ushort*)(ws + 167772160 + 67108864 + 393216);   // 384 KiB
    float*  kvbuf  = (float*)d_out;                  // 288 KB scratch; gemm_proj overwrites
    unsigned int* qmeta = (unsigned int*)((char*)d_out + 524288);  // cnt + 8MB worklist

    conv_w<<<dim3(768), 128, 0, stream>>>(w_qkv, Awh, Awl);
    zero_cnt<<<1, 64, 0, stream>>>(qmeta);
    conv_x<<<dim3(64, 4, NB), 256, 0, stream>>>(x, XTh, XTl);

    gemm_q<<<dim3(1024), 256, 0, stream>>>(
        Awh, Awl, XTh, XTl, qkv_bf, qplane, qmeta);
    gemm_kv<<<dim3(2048), 256, 0, stream>>>(Awh, XTh, qkv_bf);

    qfix2_kernel<<<dim3(1024), 256, 0, stream>>>(qplane, w_qkv, x, qmeta);

    dwpw_kernel<<<dim3(4, 96, NB), 512, 0, stream>>>(qkv_bf, w_dw, w_pw, agg_bf);

    kv_kernel<<<dim3(64, NB), 256, 0, stream>>>(qkv_bf, agg_bf, kvbuf);

    attn_out_kernel<<<dim3(16, 64, NB), 256, 0, stream>>>(qplane, agg_bf, kvbuf);

    gemm_proj<<<dim3(64, 4, NB), 256, 0, stream>>>(
        w_proj, agg_bf, y, bn_g, bn_b, bn_m, bn_v);
}

// Round 7
// 411.335 us; speedup vs baseline: 1.1201x; 1.1201x over previous
//
#include <hip/hip_runtime.h>
#include <hip/hip_bf16.h>

// LiteMSA pipeline, MI355X gfx950.
// B=16, Cin=256, Cqkv=768, H=W=64 (P=4096), heads=64 (24 ch: q8,k8,v8),
// out 512 ch -> proj 256 ch + BN. Output y fp32.
//
// GEMM1 (v7): REFUSED gemm (v5 structure: one 3072-block grid, q+kv block
// types co-resident -> block-level overlap; v6's split serialized them and
// lost 85us) + v6's sparse qfix (detection in q epilogue -> worklist ->
// qfix2 fp64, replaces the 72us full-tensor scan).
// Pre-convert w_qkv/x to bf16 hi/lo once (conv_w, conv_x), swizzled (16B
// slot ^= (row>>1)&3 per 64B window); stage via global_load_lds w=16,
// double-buffered, counted vmcnt(8|4) + raw s_barrier pair per K-step.
// XCD-contiguous swizzle: 6 mt-blocks sharing a B-slice on one XCD.
//
// ws (256 MiB):
//   qkv_bf [0,96M)    bf16 768ch
//   qplane [96M,160M) fp32 256ch (q of heads 0-31)
//   agg_bf [160M,256M) bf16 768ch; ALIASED before dwpw by:
//     XTh [+0,32M) XTl [+32M,64M)  x^T bf16 hi/lo [b][4096][256] swizzled
//     Awh/Awl [+64M, +64.75M)      w_qkv bf16 hi/lo [768 virt][256] swizzled
// d_out: kvbuf 288K scratch at head; qmeta (cnt + worklist) at +512K
// (consumed by qfix2 before kv/attn run; gemm_proj overwrites all).

#define NB 16
#define CQKV 768
#define P4096 4096
#define QFIX_CAP (1u << 21)

typedef __bf16 bf16x8 __attribute__((ext_vector_type(8)));
typedef float f32x4 __attribute__((ext_vector_type(4)));

#define MFMA_BF16 __builtin_amdgcn_mfma_f32_16x16x32_bf16

__device__ __forceinline__ ushort f2bf(float f) {
    union { float f; unsigned int u; } x; x.f = f;
    unsigned int u = x.u;
    unsigned int r = (u + 0x7FFFu + ((u >> 16) & 1u)) >> 16;
    return (ushort)r;
}
__device__ __forceinline__ float bf2f(ushort u) {
    union { unsigned int u; float f; } x; x.u = ((unsigned int)u) << 16;
    return x.f;
}
__device__ __forceinline__ unsigned int pk2bf(float x, float y) {
    __hip_bfloat162 h = __float22bfloat162_rn(make_float2(x, y));  // v_cvt_pk_bf16_f32 (RNE)
    union { __hip_bfloat162 b; unsigned int u; } c; c.b = h; return c.u;
}
// 8 fp32 -> bf16 hi (one b128 LDS write)
__device__ __forceinline__ void stage_hi8(const float* v, ushort* dh) {
    union { unsigned int u[4]; uint4 q; } H;
    #pragma unroll
    for (int i = 0; i < 4; i++) H.u[i] = pk2bf(v[2 * i], v[2 * i + 1]);
    *(uint4*)dh = H.q;
}

__device__ __forceinline__ void gload16(void* lds, const void* g) {
    __builtin_amdgcn_global_load_lds(
        (const __attribute__((address_space(1))) void*)g,
        (__attribute__((address_space(3))) void*)lds, 16, 0, 0);
}

// ---------------- conv_w: w_qkv -> virt-row-ordered, swizzled bf16 hi/lo ----------------
// virt rows: 0..255 q (phys=(v>>3)*24+v&7), 256..767 kv (phys=(v2>>4)*24+8+v2&15).
__global__ __launch_bounds__(128) void conv_w(
    const float* __restrict__ W, ushort* __restrict__ Ah, ushort* __restrict__ Al)
{
    const int rv = blockIdx.x;     // 0..767
    const int t  = threadIdx.x;    // 0..127 -> c pair
    int phys;
    if (rv < 256) phys = (rv >> 3) * 24 + (rv & 7);
    else { int r2 = rv - 256; phys = (r2 >> 4) * 24 + 8 + (r2 & 15); }
    int c = t * 2;
    float w0 = W[(size_t)phys * 256 + c];
    float w1 = W[(size_t)phys * 256 + c + 1];
    unsigned int h = pk2bf(w0, w1);
    float f0 = __uint_as_float(h << 16);
    float f1 = __uint_as_float(h & 0xffff0000u);
    unsigned int l = pk2bf(w0 - f0, w1 - f1);
    int sl = ((c >> 3) & 3) ^ ((rv >> 1) & 3);
    int idx = (c & ~31) + sl * 8 + (c & 7);
    *(unsigned int*)&Ah[(size_t)rv * 256 + idx] = h;
    *(unsigned int*)&Al[(size_t)rv * 256 + idx] = l;
}

// ---------------- conv_x: x [b][256][4096] f32 -> XT hi/lo [b][4096][256] bf16, swizzled ----------------
__global__ __launch_bounds__(256) void conv_x(
    const float* __restrict__ X, ushort* __restrict__ XTh, ushort* __restrict__ XTl)
{
    const int pt = blockIdx.x;        // 0..63
    const int ct = blockIdx.y;        // 0..3
    const int b  = blockIdx.z;
    const int t  = threadIdx.x;
    const int p0 = pt * 64, c0 = ct * 64;

    __shared__ float tile[64][65];

    {
        int cr = t >> 2, pc = (t & 3) * 16;
        const float* xr = X + ((size_t)b * 256 + c0 + cr) * P4096 + p0 + pc;
        float4 v0 = *(const float4*)xr;
        float4 v1 = *(const float4*)(xr + 4);
        float4 v2 = *(const float4*)(xr + 8);
        float4 v3 = *(const float4*)(xr + 12);
        float* d = &tile[cr][pc];
        d[0]=v0.x; d[1]=v0.y; d[2]=v0.z; d[3]=v0.w;
        d[4]=v1.x; d[5]=v1.y; d[6]=v1.z; d[7]=v1.w;
        d[8]=v2.x; d[9]=v2.y; d[10]=v2.z; d[11]=v2.w;
        d[12]=v3.x; d[13]=v3.y; d[14]=v3.z; d[15]=v3.w;
    }
    __syncthreads();

    #pragma unroll
    for (int pass = 0; pass < 2; pass++) {
        int tp = t >> 2;
        int cc = (t & 3) + pass * 4;      // 0..7 chunk of 8 c
        int p  = p0 + tp;
        float v[8];
        #pragma unroll
        for (int j = 0; j < 8; j++) v[j] = tile[cc * 8 + j][tp];
        union { unsigned int u[4]; uint4 q; } H, L;
        #pragma unroll
        for (int i = 0; i < 4; i++) {
            unsigned int h = pk2bf(v[2 * i], v[2 * i + 1]);
            H.u[i] = h;
            float f0 = __uint_as_float(h << 16);
            float f1 = __uint_as_float(h & 0xffff0000u);
            L.u[i] = pk2bf(v[2 * i] - f0, v[2 * i + 1] - f1);
        }
        int c = c0 + cc * 8;
        int sl = ((c >> 3) & 3) ^ ((p >> 1) & 3);
        size_t idx = ((size_t)b * P4096 + p) * 256 + (c & ~31) + sl * 8;
        *(uint4*)&XTh[idx] = H.q;
        *(uint4*)&XTl[idx] = L.q;
    }
}

// ---------------- zero worklist counter ----------------
__global__ void zero_cnt(unsigned int* qmeta) { if (threadIdx.x == 0) qmeta[0] = 0; }

// ---------------- gemm_fused: all 768 virt rows; q tiles 3-term, kv tiles 1-term ----------------
// 128x128 tile, BK=32, 256 thr = 4 waves (2x2). Stage via global_load_lds w=16,
// double-buffered with COUNTED vmcnt: issue next-tile loads, s_waitcnt
// vmcnt(8|4) (previous tile landed, new stays in flight), raw s_barrier,
// ds_read+MFMA, raw s_barrier. Grid 1-D 3072, XCD swizzle lg=(hw&7)*384+(hw>>3).
// q epilogue also emits the sparse qfix worklist (|v|<1e-4, ~4k entries).
__global__ __launch_bounds__(256, 2) void gemm_fused(
    const ushort* __restrict__ Ah, const ushort* __restrict__ Al,
    const ushort* __restrict__ Bh, const ushort* __restrict__ Bl,
    ushort* __restrict__ Cbf, float* __restrict__ qplane,
    unsigned int* __restrict__ qmeta)
{
    const int hw = blockIdx.x;                 // 0..3071
    const int lg = (hw & 7) * 384 + (hw >> 3); // XCD-contiguous logical id
    const int mt = lg % 6;
    const int rem = lg / 6;                    // 0..511
    const int n0 = (rem & 31) * 128;
    const int b  = rem >> 5;
    const int t  = threadIdx.x;
    const int wave = t >> 6, lane = t & 63, quad = lane >> 4, l15 = lane & 15;
    const int wr = wave >> 1, wc = wave & 1;
    const int M0 = mt * 128;

    __shared__ __align__(16) ushort AsH[2][4096];
    __shared__ __align__(16) ushort AsL[2][4096];
    __shared__ __align__(16) ushort BsH[2][4096];
    __shared__ __align__(16) ushort BsL[2][4096];

    int aoff[4], boff[4];
    #pragma unroll
    for (int i = 0; i < 4; i++) {
        int ra = wr * 64 + i * 16 + l15;
        aoff[i] = ra * 64 + ((quad ^ ((ra >> 1) & 3)) << 4);
        int rb = wc * 64 + i * 16 + l15;
        boff[i] = rb * 64 + ((quad ^ ((rb >> 1) & 3)) << 4);
    }

    const int srow = t >> 2;               // 0..63
    const int schunk = (t & 3) * 8;        // ushort offset in 32-ushort window
    const size_t abase = (size_t)(M0 + srow) * 256 + schunk;
    const size_t bbase = ((size_t)b * P4096 + n0 + srow) * 256 + schunk;
    const int ldsoff = wave * 1024;        // bytes; +i*4096

    f32x4 acc[4][4];
    #pragma unroll
    for (int mi = 0; mi < 4; mi++)
        #pragma unroll
        for (int nj = 0; nj < 4; nj++)
            #pragma unroll
            for (int r = 0; r < 4; r++) acc[mi][nj][r] = 0.0f;

    if (mt < 2) {
        // ---- q rows: 3-term split; 8 global_load_lds per stage ----
        auto stageQ = [&](int d, int kw) {
            #pragma unroll
            for (int i = 0; i < 2; i++) {
                int lo = ldsoff + i * 4096;
                size_t so = (size_t)(i * 64) * 256 + (size_t)kw * 32;
                gload16((char*)AsH[d] + lo, Ah + abase + so);
                gload16((char*)AsL[d] + lo, Al + abase + so);
                gload16((char*)BsH[d] + lo, Bh + bbase + so);
                gload16((char*)BsL[d] + lo, Bl + bbase + so);
            }
        };
        stageQ(0, 0);
        for (int kw = 0; kw < 8; kw++) {
            int cur = kw & 1;
            if (kw < 7) {
                stageQ(cur ^ 1, kw + 1);
                asm volatile("s_waitcnt vmcnt(8)" ::: "memory");
            } else {
                asm volatile("s_waitcnt vmcnt(0)" ::: "memory");
            }
            __builtin_amdgcn_s_barrier();
            bf16x8 ah[4], al[4];
            #pragma unroll
            for (int mi = 0; mi < 4; mi++) {
                ah[mi] = *(const bf16x8*)((const char*)AsH[cur] + aoff[mi]);
                al[mi] = *(const bf16x8*)((const char*)AsL[cur] + aoff[mi]);
            }
            #pragma unroll
            for (int nj = 0; nj < 4; nj++) {
                bf16x8 bh = *(const bf16x8*)((const char*)BsH[cur] + boff[nj]);
                bf16x8 bl = *(const bf16x8*)((const char*)BsL[cur] + boff[nj]);
                #pragma unroll
                for (int mi = 0; mi < 4; mi++) {
                    acc[mi][nj] = MFMA_BF16(ah[mi], bh, acc[mi][nj], 0, 0, 0);
                    acc[mi][nj] = MFMA_BF16(al[mi], bh, acc[mi][nj], 0, 0, 0);
                    acc[mi][nj] = MFMA_BF16(ah[mi], bl, acc[mi][nj], 0, 0, 0);
                }
            }
            __builtin_amdgcn_s_barrier();   // reads of buf[cur] done before next overwrite
        }
        unsigned int* qlist = qmeta + 16;
        #pragma unroll
        for (int mi = 0; mi < 4; mi++)
            #pragma unroll
            for (int nj = 0; nj < 4; nj++)
                #pragma unroll
                for (int r = 0; r < 4; r++) {
                    int rv = M0 + wr * 64 + mi * 16 + quad * 4 + r;
                    int rp = (rv >> 3) * 24 + (rv & 7);
                    int col = n0 + wc * 64 + nj * 16 + l15;
                    float v = acc[mi][nj][r];
                    Cbf[((size_t)b * CQKV + rp) * P4096 + col] = f2bf(v);
                    qplane[((size_t)b * 256 + rv) * P4096 + col] = v;
                    if (fabsf(v) < 1e-4f) {   // sparse qfix worklist (~2.5e-4 hit rate)
                        unsigned int idx = atomicAdd(qmeta, 1u);
                        if (idx < QFIX_CAP)
                            qlist[idx] = (unsigned int)(((b * 256 + rv) << 12) | col);
                    }
                }
    } else {
        // ---- k/v rows: single term; 4 global_load_lds per stage ----
        auto stageKV = [&](int d, int kw) {
            #pragma unroll
            for (int i = 0; i < 2; i++) {
                int lo = ldsoff + i * 4096;
                size_t so = (size_t)(i * 64) * 256 + (size_t)kw * 32;
                gload16((char*)AsH[d] + lo, Ah + abase + so);
                gload16((char*)BsH[d] + lo, Bh + bbase + so);
            }
        };
        stageKV(0, 0);
        for (int kw = 0; kw < 8; kw++) {
            int cur = kw & 1;
            if (kw < 7) {
                stageKV(cur ^ 1, kw + 1);
                asm volatile("s_waitcnt vmcnt(4)" ::: "memory");
            } else {
                asm volatile("s_waitcnt vmcnt(0)" ::: "memory");
            }
            __builtin_amdgcn_s_barrier();
            bf16x8 ah[4];
            #pragma unroll
            for (int mi = 0; mi < 4; mi++)
                ah[mi] = *(const bf16x8*)((const char*)AsH[cur] + aoff[mi]);
            #pragma unroll
            for (int nj = 0; nj < 4; nj++) {
                bf16x8 bh = *(const bf16x8*)((const char*)BsH[cur] + boff[nj]);
                #pragma unroll
                for (int mi = 0; mi < 4; mi++)
                    acc[mi][nj] = MFMA_BF16(ah[mi], bh, acc[mi][nj], 0, 0, 0);
            }
            __builtin_amdgcn_s_barrier();
        }
        #pragma unroll
        for (int mi = 0; mi < 4; mi++)
            #pragma unroll
            for (int nj = 0; nj < 4; nj++)
                #pragma unroll
                for (int r = 0; r < 4; r++) {
                    int rv2 = (M0 - 256) + wr * 64 + mi * 16 + quad * 4 + r;
                    int rp = (rv2 >> 4) * 24 + 8 + (rv2 & 15);
                    int col = n0 + wc * 64 + nj * 16 + l15;
                    Cbf[((size_t)b * CQKV + rp) * P4096 + col] = f2bf(acc[mi][nj][r]);
                }
    }
}

// ---------------- qfix2: sparse fp64 recompute, one wave per worklist entry ----------------
__global__ __launch_bounds__(256) void qfix2_kernel(
    float* __restrict__ qplane, const float* __restrict__ w_qkv,
    const float* __restrict__ x, const unsigned int* __restrict__ qmeta)
{
    unsigned int n = qmeta[0];
    if (n > QFIX_CAP) n = QFIX_CAP;
    const unsigned int* list = qmeta + 16;
    const int wave = threadIdx.x >> 6, lane = threadIdx.x & 63;
    for (unsigned int e = blockIdx.x * 4 + wave; e < n; e += gridDim.x * 4) {
        unsigned int i = list[e];
        int p   = (int)(i & 4095);
        int qch = (int)((i >> 12) & 255);
        int b   = (int)(i >> 20);
        int row = (qch >> 3) * 24 + (qch & 7);
        const float* wr = w_qkv + (size_t)row * 256;
        const float* xr = x + (size_t)b * 256 * P4096 + p;
        double s = 0.0;
        #pragma unroll
        for (int j = 0; j < 4; j++) {
            int c = lane * 4 + j;
            s += (double)wr[c] * (double)xr[(size_t)c * P4096];
        }
        #pragma unroll
        for (int off = 32; off > 0; off >>= 1) s += __shfl_xor(s, off, 64);
        if (lane == 0)
            qplane[((size_t)(b * 256 + qch)) * P4096 + p] = (float)s;
    }
}

// ---------------- dw 3x3 + grouped pw (bf16; feeds only heads 32-63) ----------------
__global__ __launch_bounds__(512, 8) void dwpw_kernel(
    const ushort* __restrict__ qkv, const float* __restrict__ wdw,
    const float* __restrict__ wpw, ushort* __restrict__ agg)
{
    const int rt = blockIdx.x;    // 0..3 (16 output rows each)
    const int g  = blockIdx.y;    // 0..95
    const int b  = blockIdx.z;
    const int t  = threadIdx.x;   // 0..511
    const int r0 = rt * 16;
    const int cg = g * 8;

    __shared__ __align__(16) ushort tile[8][18][80];   // 23040 B

    const ushort* src = qkv + ((size_t)(b * CQKV + cg)) * P4096;

    if (t < 288) {
        int ch = t / 36;
        int rr = (t % 36) >> 1;
        int side = t & 1;
        *(uint4*)&tile[ch][rr][side * 72] = make_uint4(0, 0, 0, 0);
    }
    #pragma unroll
    for (int i = 0; i < 3; i++) {
        int id = t + i * 512;
        if (id < 1152) {
            int ch  = id / 144;
            int rem = id - ch * 144;
            int rr  = rem >> 3;
            int oct = (rem & 7) * 8;
            int grow = r0 - 1 + rr;
            uint4 v = make_uint4(0, 0, 0, 0);
            if (grow >= 0 && grow < 64)
                v = *(const uint4*)(src + (size_t)ch * P4096 + (size_t)grow * 64 + oct);
            *(uint4*)&tile[ch][rr][8 + oct] = v;
        }
    }
    __syncthreads();

    const int kc  = t & 31;        // col pair: cols 2kc, 2kc+1
    const int row = t >> 5;        // 0..15
    const float* wdwg = wdw + (size_t)cg * 9;   // block-uniform -> s_load
    const float* wpwg = wpw + (size_t)cg * 8;

    float acc0[8], acc1[8];
    #pragma unroll
    for (int oi = 0; oi < 8; oi++) { acc0[oi] = 0.0f; acc1[oi] = 0.0f; }

    #pragma unroll
    for (int c = 0; c < 8; c++) {
        float dv0 = 0.0f, dv1 = 0.0f;
        #pragma unroll
        for (int dy = 0; dy < 3; dy++) {
            const ushort* rp = &tile[c][row + dy][2 * kc + 4];
            unsigned int u1 = *(const unsigned int*)(rp + 2);
            unsigned int u2 = *(const unsigned int*)(rp + 4);
            unsigned int u3 = *(const unsigned int*)(rp + 6);
            float xm1 = __uint_as_float(u1 & 0xffff0000u);
            float x0  = __uint_as_float(u2 << 16);
            float x1  = __uint_as_float(u2 & 0xffff0000u);
            float x2  = __uint_as_float(u3 << 16);
            float w0 = wdwg[c * 9 + dy * 3 + 0];
            float w1 = wdwg[c * 9 + dy * 3 + 1];
            float w2 = wdwg[c * 9 + dy * 3 + 2];
            dv0 = fmaf(w0, xm1, dv0); dv0 = fmaf(w1, x0, dv0); dv0 = fmaf(w2, x1, dv0);
            dv1 = fmaf(w0, x0,  dv1); dv1 = fmaf(w1, x1, dv1); dv1 = fmaf(w2, x2, dv1);
        }
        #pragma unroll
        for (int oi = 0; oi < 8; oi++) {
            float w = wpwg[oi * 8 + c];
            acc0[oi] = fmaf(w, dv0, acc0[oi]);
            acc1[oi] = fmaf(w, dv1, acc1[oi]);
        }
    }

    size_t obase = ((size_t)(b * CQKV + cg)) * P4096 + (size_t)(r0 + row) * 64 + 2 * kc;
    #pragma unroll
    for (int oi = 0; oi < 8; oi++) {
        unsigned int u = (unsigned int)f2bf(acc0[oi]) |
                         ((unsigned int)f2bf(acc1[oi]) << 16);
        *(unsigned int*)&agg[obase + (size_t)oi * P4096] = u;
    }
}

// ---------------- kv[b,h,d,e] = sum_p relu(k_d)*v_e  (v_8 = 1) ----------------
__global__ __launch_bounds__(256) void kv_kernel(
    const ushort* __restrict__ qkv, const ushort* __restrict__ agg,
    float* __restrict__ kv)
{
    const int h = blockIdx.x, b = blockIdx.y, t = threadIdx.x;
    const ushort* src = (h < 32)
        ? qkv + ((size_t)(b * CQKV + h * 24)) * P4096
        : agg + ((size_t)(b * CQKV + (h - 32) * 24)) * P4096;

    float acc[72];
    #pragma unroll
    for (int i = 0; i < 72; i++) acc[i] = 0.0f;

    for (int pi = 0; pi < 16; pi++) {
        int p = t + pi * 256;
        float kvv[8], vv[8];
        #pragma unroll
        for (int d = 0; d < 8; d++) {
            float xk = bf2f(src[(size_t)(8 + d) * P4096 + p]);
            kvv[d] = xk > 0.0f ? xk : 0.0f;
        }
        #pragma unroll
        for (int e = 0; e < 8; e++) vv[e] = bf2f(src[(size_t)(16 + e) * P4096 + p]);
        #pragma unroll
        for (int d = 0; d < 8; d++) {
            #pragma unroll
            for (int e = 0; e < 8; e++) acc[d * 9 + e] += kvv[d] * vv[e];
            acc[d * 9 + 8] += kvv[d];
        }
    }

    #pragma unroll
    for (int i = 0; i < 72; i++) {
        float v = acc[i];
        #pragma unroll
        for (int off = 32; off > 0; off >>= 1) v += __shfl_xor(v, off, 64);
        acc[i] = v;
    }
    __shared__ float part[4][72];
    int wave = t >> 6, lane = t & 63;
    if (lane == 0) {
        #pragma unroll
        for (int i = 0; i < 72; i++) part[wave][i] = acc[i];
    }
    __syncthreads();
    if (t < 72)
        kv[((size_t)b * 64 + h) * 72 + t] = part[0][t] + part[1][t] + part[2][t] + part[3][t];
}

// ---------------- attn: out = (q.kv)_e / ((q.kv)_8 + 1e-15) ----------------
__global__ __launch_bounds__(256) void attn_out_kernel(
    const float* __restrict__ qplane, ushort* __restrict__ agg,
    const float* __restrict__ kv)
{
    const int pt = blockIdx.x, h = blockIdx.y, b = blockIdx.z, t = threadIdx.x;
    __shared__ float kvs[72];
    if (t < 72) kvs[t] = kv[((size_t)b * 64 + h) * 72 + t];
    __syncthreads();

    const bool lohead = (h < 32);
    const float* srcf = lohead
        ? qplane + ((size_t)(b * 256 + h * 8)) * P4096 : nullptr;
    const ushort* srcb = lohead ? nullptr
        : agg + ((size_t)(b * CQKV + (h - 32) * 24)) * P4096;

    int p = pt * 256 + t;
    float num[8]; float den = 0.0f;
    #pragma unroll
    for (int e = 0; e < 8; e++) num[e] = 0.0f;
    #pragma unroll
    for (int d = 0; d < 8; d++) {
        float q = lohead ? srcf[(size_t)d * P4096 + p]
                         : bf2f(srcb[(size_t)d * P4096 + p]);
        q = q > 0.0f ? q : 0.0f;
        #pragma unroll
        for (int e = 0; e < 8; e++) num[e] += q * kvs[d * 9 + e];
        den += q * kvs[d * 9 + 8];
    }
    float rd = 1.0f / (den + 1e-15f);
    ushort* dst = agg + ((size_t)(b * CQKV + (h / 2) * 24 + 8 + (h % 2) * 8)) * P4096 + p;
    #pragma unroll
    for (int e = 0; e < 8; e++)
        dst[(size_t)e * P4096] = f2bf(num[e] * rd);
}

// ---------------- GEMM3: y = W_proj(256x512) @ out[b](512x4096), bf16, BN ----------------
__global__ __launch_bounds__(256) void gemm_proj(
    const float* __restrict__ A,       // 256 x 512 fp32
    const ushort* __restrict__ Bagg,   // out in agg's k/v slots, map(k)=(k/16)*24+8+(k%16)
    float* __restrict__ Y,
    const float* __restrict__ bn_g, const float* __restrict__ bn_b,
    const float* __restrict__ bn_m, const float* __restrict__ bn_v)
{
    const int n0 = blockIdx.x * 64;
    const int m0 = blockIdx.y * 64;
    const int b  = blockIdx.z;
    const int t  = threadIdx.x;
    const int wave = t >> 6, lane = t & 63, quad = lane >> 4, l15 = lane & 15;

    __shared__ __align__(16) ushort As[64][40];
    __shared__ __align__(16) ushort Bs[64][40];

    f32x4 acc[4];
    #pragma unroll
    for (int nt = 0; nt < 4; nt++)
        #pragma unroll
        for (int r = 0; r < 4; r++) acc[nt][r] = 0.0f;

    const int am = t >> 2, ak = (t & 3) * 8;
    const int bn = t & 63, kg = (t >> 6) * 8;

    for (int k0 = 0; k0 < 512; k0 += 32) {
        float av[8];
        *(float4*)&av[0] = *(const float4*)(A + (size_t)(m0 + am) * 512 + k0 + ak);
        *(float4*)&av[4] = *(const float4*)(A + (size_t)(m0 + am) * 512 + k0 + ak + 4);
        ushort bu[8];
        #pragma unroll
        for (int i = 0; i < 8; i++) {
            int kk = k0 + kg + i;
            int amch = (kk >> 4) * 24 + 8 + (kk & 15);
            bu[i] = Bagg[((size_t)b * CQKV + amch) * P4096 + n0 + bn];
        }

        __syncthreads();
        stage_hi8(av, &As[am][ak]);
        {
            union { ushort us[8]; uint4 q; } Bp;
            #pragma unroll
            for (int i = 0; i < 8; i++) Bp.us[i] = bu[i];
            *(uint4*)&Bs[bn][kg] = Bp.q;
        }
        __syncthreads();

        bf16x8 af = *(const bf16x8*)&As[wave * 16 + l15][quad * 8];
        #pragma unroll
        for (int nt = 0; nt < 4; nt++) {
            bf16x8 bf = *(const bf16x8*)&Bs[nt * 16 + l15][quad * 8];
            acc[nt] = MFMA_BF16(af, bf, acc[nt], 0, 0, 0);
        }
    }

    #pragma unroll
    for (int nt = 0; nt < 4; nt++) {
        #pragma unroll
        for (int r = 0; r < 4; r++) {
            int row = m0 + wave * 16 + quad * 4 + r;
            int col = n0 + nt * 16 + l15;
            float inv = bn_g[row] / sqrtf(bn_v[row] + 1e-5f);
            float v = acc[nt][r] * inv + (bn_b[row] - bn_m[row] * inv);
            Y[((size_t)b * 256 + row) * P4096 + col] = v;
        }
    }
}

// ---------------- launch ----------------
extern "C" void kernel_launch(void* const* d_in, const int* in_sizes, int n_in,
                              void* d_out, int out_size, void* d_ws, size_t ws_size,
                              hipStream_t stream) {
    const float* x      = (const float*)d_in[0];
    const float* w_qkv  = (const float*)d_in[1];
    const float* w_dw   = (const float*)d_in[2];
    const float* w_pw   = (const float*)d_in[3];
    const float* w_proj = (const float*)d_in[4];
    const float* bn_g   = (const float*)d_in[5];
    const float* bn_b   = (const float*)d_in[6];
    const float* bn_m   = (const float*)d_in[7];
    const float* bn_v   = (const float*)d_in[8];
    float* y = (float*)d_out;

    char* ws = (char*)d_ws;
    ushort* qkv_bf = (ushort*)(ws);                  // 96 MiB: bf16 768ch
    float*  qplane = (float*) (ws + 100663296);      // 64 MiB: fp32 q (heads 0-31)
    ushort* agg_bf = (ushort*)(ws + 167772160);      // 96 MiB: agg; k/v slots reused for out
    // aliases inside agg region, dead once dwpw runs:
    ushort* XTh = (ushort*)(ws + 167772160);                       // 32 MiB
    ushort* XTl = (ushort*)(ws + 167772160 + 33554432);            // 32 MiB
    ushort* Awh = (ushort*)(ws + 167772160 + 67108864);            // 384 KiB
    ushort* Awl = (ushort*)(ws + 167772160 + 67108864 + 393216);   // 384 KiB
    float*  kvbuf  = (float*)d_out;                  // 288 KB scratch; gemm_proj overwrites
    unsigned int* qmeta = (unsigned int*)((char*)d_out + 524288);  // cnt + 8MB worklist

    conv_w<<<dim3(768), 128, 0, stream>>>(w_qkv, Awh, Awl);
    zero_cnt<<<1, 64, 0, stream>>>(qmeta);
    conv_x<<<dim3(64, 4, NB), 256, 0, stream>>>(x, XTh, XTl);

    gemm_fused<<<dim3(3072), 256, 0, stream>>>(
        Awh, Awl, XTh, XTl, qkv_bf, qplane, qmeta);

    qfix2_kernel<<<dim3(1024), 256, 0, stream>>>(qplane, w_qkv, x, qmeta);

    dwpw_kernel<<<dim3(4, 96, NB), 512, 0, stream>>>(qkv_bf, w_dw, w_pw, agg_bf);

    kv_kernel<<<dim3(64, NB), 256, 0, stream>>>(qkv_bf, agg_bf, kvbuf);

    attn_out_kernel<<<dim3(16, 64, NB), 256, 0, stream>>>(qplane, agg_bf, kvbuf);

    gemm_proj<<<dim3(64, 4, NB), 256, 0, stream>>>(
        w_proj, agg_bf, y, bn_g, bn_b, bn_m, bn_v);
}

// Round 8
// 396.550 us; speedup vs baseline: 1.1619x; 1.0373x over previous
//
#include <hip/hip_runtime.h>
#include <hip/hip_bf16.h>

// LiteMSA pipeline, MI355X gfx950.
// B=16, Cin=256, Cqkv=768, H=W=64 (P=4096), heads=64 (24 ch: q8,k8,v8),
// out 512 ch -> proj 256 ch + BN. Output y fp32.
//
// v8 = v7 + modernized gemm_proj: 128x128 tile, pre-converted w_proj bf16
// (conv_wp, runs after attn_out, lives in dead qplane region), A via
// global_load_lds w=16 (swizzled storage), B via reg-transpose staging
// (16 coalesced scalar loads -> 2 ds_write_b128, pad-40 rows), issue-early/
// write-late double buffer with raw barriers. Numerics bitwise unchanged.
//
// ws (256 MiB):
//   qkv_bf [0,96M)    bf16 768ch
//   qplane [96M,160M) fp32 256ch (q of heads 0-31); REUSED after attn_out
//                     for Awp (w_proj bf16 256x512, 256KB)
//   agg_bf [160M,256M) bf16 768ch; ALIASED before dwpw by XTh/XTl/Awh/Awl
// d_out: kvbuf 288K scratch at head; qmeta (cnt + worklist) at +512K.

#define NB 16
#define CQKV 768
#define P4096 4096
#define QFIX_CAP (1u << 21)

typedef __bf16 bf16x8 __attribute__((ext_vector_type(8)));
typedef float f32x4 __attribute__((ext_vector_type(4)));

#define MFMA_BF16 __builtin_amdgcn_mfma_f32_16x16x32_bf16

__device__ __forceinline__ ushort f2bf(float f) {
    union { float f; unsigned int u; } x; x.f = f;
    unsigned int u = x.u;
    unsigned int r = (u + 0x7FFFu + ((u >> 16) & 1u)) >> 16;
    return (ushort)r;
}
__device__ __forceinline__ float bf2f(ushort u) {
    union { unsigned int u; float f; } x; x.u = ((unsigned int)u) << 16;
    return x.f;
}
__device__ __forceinline__ unsigned int pk2bf(float x, float y) {
    __hip_bfloat162 h = __float22bfloat162_rn(make_float2(x, y));  // v_cvt_pk_bf16_f32 (RNE)
    union { __hip_bfloat162 b; unsigned int u; } c; c.b = h; return c.u;
}

__device__ __forceinline__ void gload16(void* lds, const void* g) {
    __builtin_amdgcn_global_load_lds(
        (const __attribute__((address_space(1))) void*)g,
        (__attribute__((address_space(3))) void*)lds, 16, 0, 0);
}

// ---------------- conv_w: w_qkv -> virt-row-ordered, swizzled bf16 hi/lo ----------------
// virt rows: 0..255 q (phys=(v>>3)*24+v&7), 256..767 kv (phys=(v2>>4)*24+8+v2&15).
__global__ __launch_bounds__(128) void conv_w(
    const float* __restrict__ W, ushort* __restrict__ Ah, ushort* __restrict__ Al)
{
    const int rv = blockIdx.x;     // 0..767
    const int t  = threadIdx.x;    // 0..127 -> c pair
    int phys;
    if (rv < 256) phys = (rv >> 3) * 24 + (rv & 7);
    else { int r2 = rv - 256; phys = (r2 >> 4) * 24 + 8 + (r2 & 15); }
    int c = t * 2;
    float w0 = W[(size_t)phys * 256 + c];
    float w1 = W[(size_t)phys * 256 + c + 1];
    unsigned int h = pk2bf(w0, w1);
    float f0 = __uint_as_float(h << 16);
    float f1 = __uint_as_float(h & 0xffff0000u);
    unsigned int l = pk2bf(w0 - f0, w1 - f1);
    int sl = ((c >> 3) & 3) ^ ((rv >> 1) & 3);
    int idx = (c & ~31) + sl * 8 + (c & 7);
    *(unsigned int*)&Ah[(size_t)rv * 256 + idx] = h;
    *(unsigned int*)&Al[(size_t)rv * 256 + idx] = l;
}

// ---------------- conv_wp: w_proj 256x512 -> swizzled bf16 ----------------
__global__ __launch_bounds__(256) void conv_wp(
    const float* __restrict__ W, ushort* __restrict__ Awp)
{
    const int m = blockIdx.x;      // 0..255
    const int t = threadIdx.x;     // 0..255 -> c pair
    int c = t * 2;
    float w0 = W[(size_t)m * 512 + c];
    float w1 = W[(size_t)m * 512 + c + 1];
    unsigned int h = pk2bf(w0, w1);
    int sl = ((c >> 3) & 3) ^ ((m >> 1) & 3);
    int idx = (c & ~31) + sl * 8 + (c & 7);
    *(unsigned int*)&Awp[(size_t)m * 512 + idx] = h;
}

// ---------------- conv_x: x [b][256][4096] f32 -> XT hi/lo [b][4096][256] bf16, swizzled ----------------
__global__ __launch_bounds__(256) void conv_x(
    const float* __restrict__ X, ushort* __restrict__ XTh, ushort* __restrict__ XTl)
{
    const int pt = blockIdx.x;        // 0..63
    const int ct = blockIdx.y;        // 0..3
    const int b  = blockIdx.z;
    const int t  = threadIdx.x;
    const int p0 = pt * 64, c0 = ct * 64;

    __shared__ float tile[64][65];

    {
        int cr = t >> 2, pc = (t & 3) * 16;
        const float* xr = X + ((size_t)b * 256 + c0 + cr) * P4096 + p0 + pc;
        float4 v0 = *(const float4*)xr;
        float4 v1 = *(const float4*)(xr + 4);
        float4 v2 = *(const float4*)(xr + 8);
        float4 v3 = *(const float4*)(xr + 12);
        float* d = &tile[cr][pc];
        d[0]=v0.x; d[1]=v0.y; d[2]=v0.z; d[3]=v0.w;
        d[4]=v1.x; d[5]=v1.y; d[6]=v1.z; d[7]=v1.w;
        d[8]=v2.x; d[9]=v2.y; d[10]=v2.z; d[11]=v2.w;
        d[12]=v3.x; d[13]=v3.y; d[14]=v3.z; d[15]=v3.w;
    }
    __syncthreads();

    #pragma unroll
    for (int pass = 0; pass < 2; pass++) {
        int tp = t >> 2;
        int cc = (t & 3) + pass * 4;      // 0..7 chunk of 8 c
        int p  = p0 + tp;
        float v[8];
        #pragma unroll
        for (int j = 0; j < 8; j++) v[j] = tile[cc * 8 + j][tp];
        union { unsigned int u[4]; uint4 q; } H, L;
        #pragma unroll
        for (int i = 0; i < 4; i++) {
            unsigned int h = pk2bf(v[2 * i], v[2 * i + 1]);
            H.u[i] = h;
            float f0 = __uint_as_float(h << 16);
            float f1 = __uint_as_float(h & 0xffff0000u);
            L.u[i] = pk2bf(v[2 * i] - f0, v[2 * i + 1] - f1);
        }
        int c = c0 + cc * 8;
        int sl = ((c >> 3) & 3) ^ ((p >> 1) & 3);
        size_t idx = ((size_t)b * P4096 + p) * 256 + (c & ~31) + sl * 8;
        *(uint4*)&XTh[idx] = H.q;
        *(uint4*)&XTl[idx] = L.q;
    }
}

// ---------------- zero worklist counter ----------------
__global__ void zero_cnt(unsigned int* qmeta) { if (threadIdx.x == 0) qmeta[0] = 0; }

// ---------------- gemm_fused: all 768 virt rows; q tiles 3-term, kv tiles 1-term ----------------
// 128x128 tile, BK=32, 4 waves (2x2). global_load_lds w=16, double-buffered,
// counted vmcnt(8|4) + raw s_barrier pair. Grid 3072, XCD swizzle.
// q epilogue emits sparse qfix worklist.
__global__ __launch_bounds__(256, 2) void gemm_fused(
    const ushort* __restrict__ Ah, const ushort* __restrict__ Al,
    const ushort* __restrict__ Bh, const ushort* __restrict__ Bl,
    ushort* __restrict__ Cbf, float* __restrict__ qplane,
    unsigned int* __restrict__ qmeta)
{
    const int hw = blockIdx.x;                 // 0..3071
    const int lg = (hw & 7) * 384 + (hw >> 3); // XCD-contiguous logical id
    const int mt = lg % 6;
    const int rem = lg / 6;                    // 0..511
    const int n0 = (rem & 31) * 128;
    const int b  = rem >> 5;
    const int t  = threadIdx.x;
    const int wave = t >> 6, lane = t & 63, quad = lane >> 4, l15 = lane & 15;
    const int wr = wave >> 1, wc = wave & 1;
    const int M0 = mt * 128;

    __shared__ __align__(16) ushort AsH[2][4096];
    __shared__ __align__(16) ushort AsL[2][4096];
    __shared__ __align__(16) ushort BsH[2][4096];
    __shared__ __align__(16) ushort BsL[2][4096];

    int aoff[4], boff[4];
    #pragma unroll
    for (int i = 0; i < 4; i++) {
        int ra = wr * 64 + i * 16 + l15;
        aoff[i] = ra * 64 + ((quad ^ ((ra >> 1) & 3)) << 4);
        int rb = wc * 64 + i * 16 + l15;
        boff[i] = rb * 64 + ((quad ^ ((rb >> 1) & 3)) << 4);
    }

    const int srow = t >> 2;               // 0..63
    const int schunk = (t & 3) * 8;        // ushort offset in 32-ushort window
    const size_t abase = (size_t)(M0 + srow) * 256 + schunk;
    const size_t bbase = ((size_t)b * P4096 + n0 + srow) * 256 + schunk;
    const int ldsoff = wave * 1024;        // bytes; +i*4096

    f32x4 acc[4][4];
    #pragma unroll
    for (int mi = 0; mi < 4; mi++)
        #pragma unroll
        for (int nj = 0; nj < 4; nj++)
            #pragma unroll
            for (int r = 0; r < 4; r++) acc[mi][nj][r] = 0.0f;

    if (mt < 2) {
        // ---- q rows: 3-term split; 8 global_load_lds per stage ----
        auto stageQ = [&](int d, int kw) {
            #pragma unroll
            for (int i = 0; i < 2; i++) {
                int lo = ldsoff + i * 4096;
                size_t so = (size_t)(i * 64) * 256 + (size_t)kw * 32;
                gload16((char*)AsH[d] + lo, Ah + abase + so);
                gload16((char*)AsL[d] + lo, Al + abase + so);
                gload16((char*)BsH[d] + lo, Bh + bbase + so);
                gload16((char*)BsL[d] + lo, Bl + bbase + so);
            }
        };
        stageQ(0, 0);
        for (int kw = 0; kw < 8; kw++) {
            int cur = kw & 1;
            if (kw < 7) {
                stageQ(cur ^ 1, kw + 1);
                asm volatile("s_waitcnt vmcnt(8)" ::: "memory");
            } else {
                asm volatile("s_waitcnt vmcnt(0)" ::: "memory");
            }
            __builtin_amdgcn_s_barrier();
            bf16x8 ah[4], al[4];
            #pragma unroll
            for (int mi = 0; mi < 4; mi++) {
                ah[mi] = *(const bf16x8*)((const char*)AsH[cur] + aoff[mi]);
                al[mi] = *(const bf16x8*)((const char*)AsL[cur] + aoff[mi]);
            }
            #pragma unroll
            for (int nj = 0; nj < 4; nj++) {
                bf16x8 bh = *(const bf16x8*)((const char*)BsH[cur] + boff[nj]);
                bf16x8 bl = *(const bf16x8*)((const char*)BsL[cur] + boff[nj]);
                #pragma unroll
                for (int mi = 0; mi < 4; mi++) {
                    acc[mi][nj] = MFMA_BF16(ah[mi], bh, acc[mi][nj], 0, 0, 0);
                    acc[mi][nj] = MFMA_BF16(al[mi], bh, acc[mi][nj], 0, 0, 0);
                    acc[mi][nj] = MFMA_BF16(ah[mi], bl, acc[mi][nj], 0, 0, 0);
                }
            }
            __builtin_amdgcn_s_barrier();   // reads of buf[cur] done before next overwrite
        }
        unsigned int* qlist = qmeta + 16;
        #pragma unroll
        for (int mi = 0; mi < 4; mi++)
            #pragma unroll
            for (int nj = 0; nj < 4; nj++)
                #pragma unroll
                for (int r = 0; r < 4; r++) {
                    int rv = M0 + wr * 64 + mi * 16 + quad * 4 + r;
                    int rp = (rv >> 3) * 24 + (rv & 7);
                    int col = n0 + wc * 64 + nj * 16 + l15;
                    float v = acc[mi][nj][r];
                    Cbf[((size_t)b * CQKV + rp) * P4096 + col] = f2bf(v);
                    qplane[((size_t)b * 256 + rv) * P4096 + col] = v;
                    if (fabsf(v) < 1e-4f) {   // sparse qfix worklist (~2.5e-4 hit rate)
                        unsigned int idx = atomicAdd(qmeta, 1u);
                        if (idx < QFIX_CAP)
                            qlist[idx] = (unsigned int)(((b * 256 + rv) << 12) | col);
                    }
                }
    } else {
        // ---- k/v rows: single term; 4 global_load_lds per stage ----
        auto stageKV = [&](int d, int kw) {
            #pragma unroll
            for (int i = 0; i < 2; i++) {
                int lo = ldsoff + i * 4096;
                size_t so = (size_t)(i * 64) * 256 + (size_t)kw * 32;
                gload16((char*)AsH[d] + lo, Ah + abase + so);
                gload16((char*)BsH[d] + lo, Bh + bbase + so);
            }
        };
        stageKV(0, 0);
        for (int kw = 0; kw < 8; kw++) {
            int cur = kw & 1;
            if (kw < 7) {
                stageKV(cur ^ 1, kw + 1);
                asm volatile("s_waitcnt vmcnt(4)" ::: "memory");
            } else {
                asm volatile("s_waitcnt vmcnt(0)" ::: "memory");
            }
            __builtin_amdgcn_s_barrier();
            bf16x8 ah[4];
            #pragma unroll
            for (int mi = 0; mi < 4; mi++)
                ah[mi] = *(const bf16x8*)((const char*)AsH[cur] + aoff[mi]);
            #pragma unroll
            for (int nj = 0; nj < 4; nj++) {
                bf16x8 bh = *(const bf16x8*)((const char*)BsH[cur] + boff[nj]);
                #pragma unroll
                for (int mi = 0; mi < 4; mi++)
                    acc[mi][nj] = MFMA_BF16(ah[mi], bh, acc[mi][nj], 0, 0, 0);
            }
            __builtin_amdgcn_s_barrier();
        }
        #pragma unroll
        for (int mi = 0; mi < 4; mi++)
            #pragma unroll
            for (int nj = 0; nj < 4; nj++)
                #pragma unroll
                for (int r = 0; r < 4; r++) {
                    int rv2 = (M0 - 256) + wr * 64 + mi * 16 + quad * 4 + r;
                    int rp = (rv2 >> 4) * 24 + 8 + (rv2 & 15);
                    int col = n0 + wc * 64 + nj * 16 + l15;
                    Cbf[((size_t)b * CQKV + rp) * P4096 + col] = f2bf(acc[mi][nj][r]);
                }
    }
}

// ---------------- qfix2: sparse fp64 recompute, one wave per worklist entry ----------------
__global__ __launch_bounds__(256) void qfix2_kernel(
    float* __restrict__ qplane, const float* __restrict__ w_qkv,
    const float* __restrict__ x, const unsigned int* __restrict__ qmeta)
{
    unsigned int n = qmeta[0];
    if (n > QFIX_CAP) n = QFIX_CAP;
    const unsigned int* list = qmeta + 16;
    const int wave = threadIdx.x >> 6, lane = threadIdx.x & 63;
    for (unsigned int e = blockIdx.x * 4 + wave; e < n; e += gridDim.x * 4) {
        unsigned int i = list[e];
        int p   = (int)(i & 4095);
        int qch = (int)((i >> 12) & 255);
        int b   = (int)(i >> 20);
        int row = (qch >> 3) * 24 + (qch & 7);
        const float* wr = w_qkv + (size_t)row * 256;
        const float* xr = x + (size_t)b * 256 * P4096 + p;
        double s = 0.0;
        #pragma unroll
        for (int j = 0; j < 4; j++) {
            int c = lane * 4 + j;
            s += (double)wr[c] * (double)xr[(size_t)c * P4096];
        }
        #pragma unroll
        for (int off = 32; off > 0; off >>= 1) s += __shfl_xor(s, off, 64);
        if (lane == 0)
            qplane[((size_t)(b * 256 + qch)) * P4096 + p] = (float)s;
    }
}

// ---------------- dw 3x3 + grouped pw (bf16; feeds only heads 32-63) ----------------
__global__ __launch_bounds__(512, 8) void dwpw_kernel(
    const ushort* __restrict__ qkv, const float* __restrict__ wdw,
    const float* __restrict__ wpw, ushort* __restrict__ agg)
{
    const int rt = blockIdx.x;    // 0..3 (16 output rows each)
    const int g  = blockIdx.y;    // 0..95
    const int b  = blockIdx.z;
    const int t  = threadIdx.x;   // 0..511
    const int r0 = rt * 16;
    const int cg = g * 8;

    __shared__ __align__(16) ushort tile[8][18][80];   // 23040 B

    const ushort* src = qkv + ((size_t)(b * CQKV + cg)) * P4096;

    if (t < 288) {
        int ch = t / 36;
        int rr = (t % 36) >> 1;
        int side = t & 1;
        *(uint4*)&tile[ch][rr][side * 72] = make_uint4(0, 0, 0, 0);
    }
    #pragma unroll
    for (int i = 0; i < 3; i++) {
        int id = t + i * 512;
        if (id < 1152) {
            int ch  = id / 144;
            int rem = id - ch * 144;
            int rr  = rem >> 3;
            int oct = (rem & 7) * 8;
            int grow = r0 - 1 + rr;
            uint4 v = make_uint4(0, 0, 0, 0);
            if (grow >= 0 && grow < 64)
                v = *(const uint4*)(src + (size_t)ch * P4096 + (size_t)grow * 64 + oct);
            *(uint4*)&tile[ch][rr][8 + oct] = v;
        }
    }
    __syncthreads();

    const int kc  = t & 31;        // col pair: cols 2kc, 2kc+1
    const int row = t >> 5;        // 0..15
    const float* wdwg = wdw + (size_t)cg * 9;   // block-uniform -> s_load
    const float* wpwg = wpw + (size_t)cg * 8;

    float acc0[8], acc1[8];
    #pragma unroll
    for (int oi = 0; oi < 8; oi++) { acc0[oi] = 0.0f; acc1[oi] = 0.0f; }

    #pragma unroll
    for (int c = 0; c < 8; c++) {
        float dv0 = 0.0f, dv1 = 0.0f;
        #pragma unroll
        for (int dy = 0; dy < 3; dy++) {
            const ushort* rp = &tile[c][row + dy][2 * kc + 4];
            unsigned int u1 = *(const unsigned int*)(rp + 2);
            unsigned int u2 = *(const unsigned int*)(rp + 4);
            unsigned int u3 = *(const unsigned int*)(rp + 6);
            float xm1 = __uint_as_float(u1 & 0xffff0000u);
            float x0  = __uint_as_float(u2 << 16);
            float x1  = __uint_as_float(u2 & 0xffff0000u);
            float x2  = __uint_as_float(u3 << 16);
            float w0 = wdwg[c * 9 + dy * 3 + 0];
            float w1 = wdwg[c * 9 + dy * 3 + 1];
            float w2 = wdwg[c * 9 + dy * 3 + 2];
            dv0 = fmaf(w0, xm1, dv0); dv0 = fmaf(w1, x0, dv0); dv0 = fmaf(w2, x1, dv0);
            dv1 = fmaf(w0, x0,  dv1); dv1 = fmaf(w1, x1, dv1); dv1 = fmaf(w2, x2, dv1);
        }
        #pragma unroll
        for (int oi = 0; oi < 8; oi++) {
            float w = wpwg[oi * 8 + c];
            acc0[oi] = fmaf(w, dv0, acc0[oi]);
            acc1[oi] = fmaf(w, dv1, acc1[oi]);
        }
    }

    size_t obase = ((size_t)(b * CQKV + cg)) * P4096 + (size_t)(r0 + row) * 64 + 2 * kc;
    #pragma unroll
    for (int oi = 0; oi < 8; oi++) {
        unsigned int u = (unsigned int)f2bf(acc0[oi]) |
                         ((unsigned int)f2bf(acc1[oi]) << 16);
        *(unsigned int*)&agg[obase + (size_t)oi * P4096] = u;
    }
}

// ---------------- kv[b,h,d,e] = sum_p relu(k_d)*v_e  (v_8 = 1) ----------------
__global__ __launch_bounds__(256) void kv_kernel(
    const ushort* __restrict__ qkv, const ushort* __restrict__ agg,
    float* __restrict__ kv)
{
    const int h = blockIdx.x, b = blockIdx.y, t = threadIdx.x;
    const ushort* src = (h < 32)
        ? qkv + ((size_t)(b * CQKV + h * 24)) * P4096
        : agg + ((size_t)(b * CQKV + (h - 32) * 24)) * P4096;

    float acc[72];
    #pragma unroll
    for (int i = 0; i < 72; i++) acc[i] = 0.0f;

    for (int pi = 0; pi < 16; pi++) {
        int p = t + pi * 256;
        float kvv[8], vv[8];
        #pragma unroll
        for (int d = 0; d < 8; d++) {
            float xk = bf2f(src[(size_t)(8 + d) * P4096 + p]);
            kvv[d] = xk > 0.0f ? xk : 0.0f;
        }
        #pragma unroll
        for (int e = 0; e < 8; e++) vv[e] = bf2f(src[(size_t)(16 + e) * P4096 + p]);
        #pragma unroll
        for (int d = 0; d < 8; d++) {
            #pragma unroll
            for (int e = 0; e < 8; e++) acc[d * 9 + e] += kvv[d] * vv[e];
            acc[d * 9 + 8] += kvv[d];
        }
    }

    #pragma unroll
    for (int i = 0; i < 72; i++) {
        float v = acc[i];
        #pragma unroll
        for (int off = 32; off > 0; off >>= 1) v += __shfl_xor(v, off, 64);
        acc[i] = v;
    }
    __shared__ float part[4][72];
    int wave = t >> 6, lane = t & 63;
    if (lane == 0) {
        #pragma unroll
        for (int i = 0; i < 72; i++) part[wave][i] = acc[i];
    }
    __syncthreads();
    if (t < 72)
        kv[((size_t)b * 64 + h) * 72 + t] = part[0][t] + part[1][t] + part[2][t] + part[3][t];
}

// ---------------- attn: out = (q.kv)_e / ((q.kv)_8 + 1e-15) ----------------
__global__ __launch_bounds__(256) void attn_out_kernel(
    const float* __restrict__ qplane, ushort* __restrict__ agg,
    const float* __restrict__ kv)
{
    const int pt = blockIdx.x, h = blockIdx.y, b = blockIdx.z, t = threadIdx.x;
    __shared__ float kvs[72];
    if (t < 72) kvs[t] = kv[((size_t)b * 64 + h) * 72 + t];
    __syncthreads();

    const bool lohead = (h < 32);
    const float* srcf = lohead
        ? qplane + ((size_t)(b * 256 + h * 8)) * P4096 : nullptr;
    const ushort* srcb = lohead ? nullptr
        : agg + ((size_t)(b * CQKV + (h - 32) * 24)) * P4096;

    int p = pt * 256 + t;
    float num[8]; float den = 0.0f;
    #pragma unroll
    for (int e = 0; e < 8; e++) num[e] = 0.0f;
    #pragma unroll
    for (int d = 0; d < 8; d++) {
        float q = lohead ? srcf[(size_t)d * P4096 + p]
                         : bf2f(srcb[(size_t)d * P4096 + p]);
        q = q > 0.0f ? q : 0.0f;
        #pragma unroll
        for (int e = 0; e < 8; e++) num[e] += q * kvs[d * 9 + e];
        den += q * kvs[d * 9 + 8];
    }
    float rd = 1.0f / (den + 1e-15f);
    ushort* dst = agg + ((size_t)(b * CQKV + (h / 2) * 24 + 8 + (h % 2) * 8)) * P4096 + p;
    #pragma unroll
    for (int e = 0; e < 8; e++)
        dst[(size_t)e * P4096] = f2bf(num[e] * rd);
}

// ---------------- GEMM3 v2: y = W_proj @ out, 128x128 tile, dbuf pipeline ----------------
// A: Awp bf16 swizzled via global_load_lds w=16. B: agg k/v slots, reg-stage
// 16 coalesced scalar loads (16 contiguous channels per 16-k window) ->
// 2 ds_write_b128 into Bs[128][40] (pad-40: uniform bank tiling).
// Issue-early/write-late: loads for kw+1 before compute of kw; vmcnt(0) only
// after the 16 MFMAs. Grid 1024 (2 mt x 32 n x 16 b), XCD swizzle.
__global__ __launch_bounds__(256, 2) void gemm_proj(
    const ushort* __restrict__ Awp,    // 256x512 bf16 swizzled
    const ushort* __restrict__ Bagg,   // out in agg k/v slots, map(k)=(k/16)*24+8+(k%16)
    float* __restrict__ Y,
    const float* __restrict__ bn_g, const float* __restrict__ bn_b,
    const float* __restrict__ bn_m, const float* __restrict__ bn_v)
{
    const int hw = blockIdx.x;                 // 0..1023
    const int lg = (hw & 7) * 128 + (hw >> 3);
    const int mt = lg & 1;
    const int rem = lg >> 1;                   // 0..511
    const int n0 = (rem & 31) * 128;
    const int b  = rem >> 5;
    const int t  = threadIdx.x;
    const int wave = t >> 6, lane = t & 63, quad = lane >> 4, l15 = lane & 15;
    const int wr = wave >> 1, wc = wave & 1;
    const int M0 = mt * 128;

    __shared__ __align__(16) ushort As[2][4096];   // [128][32]
    __shared__ __align__(16) ushort Bs[2][5120];   // [128][40]

    int aoff[4], boff[4];
    #pragma unroll
    for (int i = 0; i < 4; i++) {
        int ra = wr * 64 + i * 16 + l15;
        aoff[i] = ra * 64 + ((quad ^ ((ra >> 1) & 3)) << 4);   // bytes
        int rb = wc * 64 + i * 16 + l15;
        boff[i] = rb * 80 + quad * 16;                          // bytes, pad-40 rows
    }

    // A staging: 2 chunks/thread, id = t + i*256 -> row=id>>2, chunk=id&3
    const int arow0 = t >> 2, achk = (t & 3) * 8;
    const size_t abase = (size_t)(M0 + arow0) * 512 + achk;       // i=0
    const size_t abase1 = (size_t)(M0 + 64 + arow0) * 512 + achk; // i=1 (row+64)
    const int ldsoffA = wave * 1024;   // bytes; +4096 for i=1

    // B staging: n = t&127, half = t>>7; 16 contiguous channels per window
    const int bn_ = t & 127, half = t >> 7;
    const size_t bchanstride = (size_t)P4096;

    f32x4 acc[4][4];
    #pragma unroll
    for (int mi = 0; mi < 4; mi++)
        #pragma unroll
        for (int nj = 0; nj < 4; nj++)
            #pragma unroll
            for (int r = 0; r < 4; r++) acc[mi][nj][r] = 0.0f;

    auto stageA = [&](int d, int kw) {
        gload16((char*)As[d] + ldsoffA,        Awp + abase  + (size_t)kw * 32);
        gload16((char*)As[d] + ldsoffA + 4096, Awp + abase1 + (size_t)kw * 32);
    };
    ushort bu[16];
    auto loadB = [&](int kw) {
        const ushort* bsrc = Bagg
            + ((size_t)b * CQKV + (size_t)(kw * 2 + half) * 24 + 8) * P4096
            + n0 + bn_;
        #pragma unroll
        for (int j = 0; j < 16; j++) bu[j] = bsrc[(size_t)j * bchanstride];
    };
    auto writeB = [&](int d) {
        union { ushort us[8]; uint4 q; } P0, P1;
        #pragma unroll
        for (int j = 0; j < 8; j++) { P0.us[j] = bu[j]; P1.us[j] = bu[8 + j]; }
        ushort* dst = &Bs[d][bn_ * 40 + half * 16];
        *(uint4*)dst = P0.q;
        *(uint4*)(dst + 8) = P1.q;
    };

    // prologue
    stageA(0, 0);
    loadB(0);
    asm volatile("s_waitcnt vmcnt(0)" ::: "memory");
    writeB(0);
    asm volatile("s_waitcnt lgkmcnt(0)" ::: "memory");
    __builtin_amdgcn_s_barrier();

    for (int kw = 0; kw < 16; kw++) {
        int cur = kw & 1;
        if (kw < 15) {
            stageA(cur ^ 1, kw + 1);
            loadB(kw + 1);
        }
        bf16x8 af[4];
        #pragma unroll
        for (int mi = 0; mi < 4; mi++)
            af[mi] = *(const bf16x8*)((const char*)As[cur] + aoff[mi]);
        #pragma unroll
        for (int nj = 0; nj < 4; nj++) {
            bf16x8 bf = *(const bf16x8*)((const char*)Bs[cur] + boff[nj]);
            #pragma unroll
            for (int mi = 0; mi < 4; mi++)
                acc[mi][nj] = MFMA_BF16(af[mi], bf, acc[mi][nj], 0, 0, 0);
        }
        __builtin_amdgcn_s_barrier();       // all reads of buf[cur] complete
        if (kw < 15) {
            asm volatile("s_waitcnt vmcnt(0)" ::: "memory");  // A(next) in LDS, B(next) regs ready
            writeB(cur ^ 1);
            asm volatile("s_waitcnt lgkmcnt(0)" ::: "memory");
        }
        __builtin_amdgcn_s_barrier();
    }

    #pragma unroll
    for (int mi = 0; mi < 4; mi++)
        #pragma unroll
        for (int nj = 0; nj < 4; nj++)
            #pragma unroll
            for (int r = 0; r < 4; r++) {
                int row = M0 + wr * 64 + mi * 16 + quad * 4 + r;
                int col = n0 + wc * 64 + nj * 16 + l15;
                float inv = bn_g[row] / sqrtf(bn_v[row] + 1e-5f);
                float v = acc[mi][nj][r] * inv + (bn_b[row] - bn_m[row] * inv);
                Y[((size_t)b * 256 + row) * P4096 + col] = v;
            }
}

// ---------------- launch ----------------
extern "C" void kernel_launch(void* const* d_in, const int* in_sizes, int n_in,
                              void* d_out, int out_size, void* d_ws, size_t ws_size,
                              hipStream_t stream) {
    const float* x      = (const float*)d_in[0];
    const float* w_qkv  = (const float*)d_in[1];
    const float* w_dw   = (const float*)d_in[2];
    const float* w_pw   = (const float*)d_in[3];
    const float* w_proj = (const float*)d_in[4];
    const float* bn_g   = (const float*)d_in[5];
    const float* bn_b   = (const float*)d_in[6];
    const float* bn_m   = (const float*)d_in[7];
    const float* bn_v   = (const float*)d_in[8];
    float* y = (float*)d_out;

    char* ws = (char*)d_ws;
    ushort* qkv_bf = (ushort*)(ws);                  // 96 MiB: bf16 768ch
    float*  qplane = (float*) (ws + 100663296);      // 64 MiB: fp32 q (heads 0-31)
    ushort* agg_bf = (ushort*)(ws + 167772160);      // 96 MiB: agg; k/v slots reused for out
    // aliases inside agg region, dead once dwpw runs:
    ushort* XTh = (ushort*)(ws + 167772160);                       // 32 MiB
    ushort* XTl = (ushort*)(ws + 167772160 + 33554432);            // 32 MiB
    ushort* Awh = (ushort*)(ws + 167772160 + 67108864);            // 384 KiB
    ushort* Awl = (ushort*)(ws + 167772160 + 67108864 + 393216);   // 384 KiB
    // alias inside qplane region, dead after attn_out:
    ushort* Awp = (ushort*)(ws + 100663296);                       // 256 KiB
    float*  kvbuf  = (float*)d_out;                  // 288 KB scratch; gemm_proj overwrites
    unsigned int* qmeta = (unsigned int*)((char*)d_out + 524288);  // cnt + 8MB worklist

    conv_w<<<dim3(768), 128, 0, stream>>>(w_qkv, Awh, Awl);
    zero_cnt<<<1, 64, 0, stream>>>(qmeta);
    conv_x<<<dim3(64, 4, NB), 256, 0, stream>>>(x, XTh, XTl);

    gemm_fused<<<dim3(3072), 256, 0, stream>>>(
        Awh, Awl, XTh, XTl, qkv_bf, qplane, qmeta);

    qfix2_kernel<<<dim3(1024), 256, 0, stream>>>(qplane, w_qkv, x, qmeta);

    dwpw_kernel<<<dim3(4, 96, NB), 512, 0, stream>>>(qkv_bf, w_dw, w_pw, agg_bf);

    kv_kernel<<<dim3(64, NB), 256, 0, stream>>>(qkv_bf, agg_bf, kvbuf);

    attn_out_kernel<<<dim3(16, 64, NB), 256, 0, stream>>>(qplane, agg_bf, kvbuf);

    conv_wp<<<dim3(256), 256, 0, stream>>>(w_proj, Awp);   // qplane dead now

    gemm_proj<<<dim3(1024), 256, 0, stream>>>(
        Awp, agg_bf, y, bn_g, bn_b, bn_m, bn_v);
}

// Round 10
// 385.800 us; speedup vs baseline: 1.1943x; 1.0279x over previous
//
#include <hip/hip_runtime.h>
#include <hip/hip_bf16.h>

// LiteMSA pipeline, MI355X gfx950.
// B=16, Cin=256, Cqkv=768, H=W=64 (P=4096), heads=64 (24 ch: q8,k8,v8),
// out 512 ch -> proj 256 ch + BN. Output y fp32.
//
// v9 = v8 + gemm_fused LDS diet (48KB: q branch single-A/double-B with
// read-A-then-stage barrier scheme; kv branch keeps counted-vmcnt dbuf in
// aliased smem) -> 3 blocks/CU; attn_out 2px/thread packed IO; zero_cnt
// folded into conv_w. Numerics bitwise unchanged.
//
// ws (256 MiB):
//   qkv_bf [0,96M)    bf16 768ch
//   qplane [96M,160M) fp32 256ch (q of heads 0-31); REUSED after attn_out
//                     for Awp (w_proj bf16 256x512, 256KB)
//   agg_bf [160M,256M) bf16 768ch; ALIASED before dwpw by XTh/XTl/Awh/Awl
// d_out: kvbuf 288K scratch at head; qmeta (cnt + worklist) at +512K.

#define NB 16
#define CQKV 768
#define P4096 4096
#define QFIX_CAP (1u << 21)

typedef __bf16 bf16x8 __attribute__((ext_vector_type(8)));
typedef float f32x4 __attribute__((ext_vector_type(4)));

#define MFMA_BF16 __builtin_amdgcn_mfma_f32_16x16x32_bf16

__device__ __forceinline__ ushort f2bf(float f) {
    union { float f; unsigned int u; } x; x.f = f;
    unsigned int u = x.u;
    unsigned int r = (u + 0x7FFFu + ((u >> 16) & 1u)) >> 16;
    return (ushort)r;
}
__device__ __forceinline__ float bf2f(ushort u) {
    union { unsigned int u; float f; } x; x.u = ((unsigned int)u) << 16;
    return x.f;
}
__device__ __forceinline__ unsigned int pk2bf(float x, float y) {
    __hip_bfloat162 h = __float22bfloat162_rn(make_float2(x, y));  // v_cvt_pk_bf16_f32 (RNE)
    union { __hip_bfloat162 b; unsigned int u; } c; c.b = h; return c.u;
}

__device__ __forceinline__ void gload16(void* lds, const void* g) {
    __builtin_amdgcn_global_load_lds(
        (const __attribute__((address_space(1))) void*)g,
        (__attribute__((address_space(3))) void*)lds, 16, 0, 0);
}

// ---------------- conv_w: w_qkv -> virt-row-ordered, swizzled bf16 hi/lo (+ zero qmeta) ----------------
// virt rows: 0..255 q (phys=(v>>3)*24+v&7), 256..767 kv (phys=(v2>>4)*24+8+v2&15).
__global__ __launch_bounds__(128) void conv_w(
    const float* __restrict__ W, ushort* __restrict__ Ah, ushort* __restrict__ Al,
    unsigned int* __restrict__ qmeta)
{
    const int rv = blockIdx.x;     // 0..767
    const int t  = threadIdx.x;    // 0..127 -> c pair
    if (rv == 0 && t == 0) qmeta[0] = 0;
    int phys;
    if (rv < 256) phys = (rv >> 3) * 24 + (rv & 7);
    else { int r2 = rv - 256; phys = (r2 >> 4) * 24 + 8 + (r2 & 15); }
    int c = t * 2;
    float w0 = W[(size_t)phys * 256 + c];
    float w1 = W[(size_t)phys * 256 + c + 1];
    unsigned int h = pk2bf(w0, w1);
    float f0 = __uint_as_float(h << 16);
    float f1 = __uint_as_float(h & 0xffff0000u);
    unsigned int l = pk2bf(w0 - f0, w1 - f1);
    int sl = ((c >> 3) & 3) ^ ((rv >> 1) & 3);
    int idx = (c & ~31) + sl * 8 + (c & 7);
    *(unsigned int*)&Ah[(size_t)rv * 256 + idx] = h;
    *(unsigned int*)&Al[(size_t)rv * 256 + idx] = l;
}

// ---------------- conv_wp: w_proj 256x512 -> swizzled bf16 ----------------
__global__ __launch_bounds__(256) void conv_wp(
    const float* __restrict__ W, ushort* __restrict__ Awp)
{
    const int m = blockIdx.x;      // 0..255
    const int t = threadIdx.x;     // 0..255 -> c pair
    int c = t * 2;
    float w0 = W[(size_t)m * 512 + c];
    float w1 = W[(size_t)m * 512 + c + 1];
    unsigned int h = pk2bf(w0, w1);
    int sl = ((c >> 3) & 3) ^ ((m >> 1) & 3);
    int idx = (c & ~31) + sl * 8 + (c & 7);
    *(unsigned int*)&Awp[(size_t)m * 512 + idx] = h;
}

// ---------------- conv_x: x [b][256][4096] f32 -> XT hi/lo [b][4096][256] bf16, swizzled ----------------
__global__ __launch_bounds__(256) void conv_x(
    const float* __restrict__ X, ushort* __restrict__ XTh, ushort* __restrict__ XTl)
{
    const int pt = blockIdx.x;        // 0..63
    const int ct = blockIdx.y;        // 0..3
    const int b  = blockIdx.z;
    const int t  = threadIdx.x;
    const int p0 = pt * 64, c0 = ct * 64;

    __shared__ float tile[64][65];

    {
        int cr = t >> 2, pc = (t & 3) * 16;
        const float* xr = X + ((size_t)b * 256 + c0 + cr) * P4096 + p0 + pc;
        float4 v0 = *(const float4*)xr;
        float4 v1 = *(const float4*)(xr + 4);
        float4 v2 = *(const float4*)(xr + 8);
        float4 v3 = *(const float4*)(xr + 12);
        float* d = &tile[cr][pc];
        d[0]=v0.x; d[1]=v0.y; d[2]=v0.z; d[3]=v0.w;
        d[4]=v1.x; d[5]=v1.y; d[6]=v1.z; d[7]=v1.w;
        d[8]=v2.x; d[9]=v2.y; d[10]=v2.z; d[11]=v2.w;
        d[12]=v3.x; d[13]=v3.y; d[14]=v3.z; d[15]=v3.w;
    }
    __syncthreads();

    #pragma unroll
    for (int pass = 0; pass < 2; pass++) {
        int tp = t >> 2;
        int cc = (t & 3) + pass * 4;      // 0..7 chunk of 8 c
        int p  = p0 + tp;
        float v[8];
        #pragma unroll
        for (int j = 0; j < 8; j++) v[j] = tile[cc * 8 + j][tp];
        union { unsigned int u[4]; uint4 q; } H, L;
        #pragma unroll
        for (int i = 0; i < 4; i++) {
            unsigned int h = pk2bf(v[2 * i], v[2 * i + 1]);
            H.u[i] = h;
            float f0 = __uint_as_float(h << 16);
            float f1 = __uint_as_float(h & 0xffff0000u);
            L.u[i] = pk2bf(v[2 * i] - f0, v[2 * i + 1] - f1);
        }
        int c = c0 + cc * 8;
        int sl = ((c >> 3) & 3) ^ ((p >> 1) & 3);
        size_t idx = ((size_t)b * P4096 + p) * 256 + (c & ~31) + sl * 8;
        *(uint4*)&XTh[idx] = H.q;
        *(uint4*)&XTl[idx] = L.q;
    }
}

// ---------------- gemm_fused: all 768 virt rows; q tiles 3-term, kv tiles 1-term ----------------
// 128x128 tile, BK=32, 4 waves (2x2), 48KB LDS -> 3 blocks/CU.
// q branch: A (L2-hot) single-buffered, B double-buffered; per step:
//   vmcnt(0); bar; read A frags; lgkmcnt(0)+schedbar; bar; stage(k+1); B+MFMA.
// kv branch: classic dbuf with counted vmcnt(4) in aliased smem (32KB).
// Grid 3072, XCD swizzle. q epilogue emits sparse qfix worklist.
__global__ __launch_bounds__(256, 3) void gemm_fused(
    const ushort* __restrict__ Ah, const ushort* __restrict__ Al,
    const ushort* __restrict__ Bh, const ushort* __restrict__ Bl,
    ushort* __restrict__ Cbf, float* __restrict__ qplane,
    unsigned int* __restrict__ qmeta)
{
    const int hw = blockIdx.x;                 // 0..3071
    const int lg = (hw & 7) * 384 + (hw >> 3); // XCD-contiguous logical id
    const int mt = lg % 6;
    const int rem = lg / 6;                    // 0..511
    const int n0 = (rem & 31) * 128;
    const int b  = rem >> 5;
    const int t  = threadIdx.x;
    const int wave = t >> 6, lane = t & 63, quad = lane >> 4, l15 = lane & 15;
    const int wr = wave >> 1, wc = wave & 1;
    const int M0 = mt * 128;

    __shared__ __align__(16) char smem[49152];   // 48 KB

    int aoff[4], boff[4];
    #pragma unroll
    for (int i = 0; i < 4; i++) {
        int ra = wr * 64 + i * 16 + l15;
        aoff[i] = ra * 64 + ((quad ^ ((ra >> 1) & 3)) << 4);
        int rb = wc * 64 + i * 16 + l15;
        boff[i] = rb * 64 + ((quad ^ ((rb >> 1) & 3)) << 4);
    }

    const int srow = t >> 2;               // 0..63
    const int schunk = (t & 3) * 8;        // ushort offset in 32-ushort window
    const size_t abase = (size_t)(M0 + srow) * 256 + schunk;
    const size_t bbase = ((size_t)b * P4096 + n0 + srow) * 256 + schunk;
    const int ldsoff = wave * 1024;        // bytes; +i*4096

    f32x4 acc[4][4];
    #pragma unroll
    for (int mi = 0; mi < 4; mi++)
        #pragma unroll
        for (int nj = 0; nj < 4; nj++)
            #pragma unroll
            for (int r = 0; r < 4; r++) acc[mi][nj][r] = 0.0f;

    if (mt < 2) {
        // ---- q rows: 3-term split; single-A (16K) + double-B (32K) ----
        char* AsH = smem;                  // 8K
        char* AsL = smem + 8192;           // 8K
        char* BsH[2] = { smem + 16384, smem + 24576 };
        char* BsL[2] = { smem + 32768, smem + 40960 };

        auto stageA = [&](int kw) {
            #pragma unroll
            for (int i = 0; i < 2; i++) {
                int lo = ldsoff + i * 4096;
                size_t so = (size_t)(i * 64) * 256 + (size_t)kw * 32;
                gload16(AsH + lo, Ah + abase + so);
                gload16(AsL + lo, Al + abase + so);
            }
        };
        auto stageB = [&](int d, int kw) {
            #pragma unroll
            for (int i = 0; i < 2; i++) {
                int lo = ldsoff + i * 4096;
                size_t so = (size_t)(i * 64) * 256 + (size_t)kw * 32;
                gload16(BsH[d] + lo, Bh + bbase + so);
                gload16(BsL[d] + lo, Bl + bbase + so);
            }
        };
        stageA(0); stageB(0, 0);
        for (int kw = 0; kw < 8; kw++) {
            int cur = kw & 1;
            asm volatile("s_waitcnt vmcnt(0)" ::: "memory");   // stage(kw) landed
            __builtin_amdgcn_s_barrier();
            bf16x8 ah[4], al[4];
            #pragma unroll
            for (int mi = 0; mi < 4; mi++) {
                ah[mi] = *(const bf16x8*)(AsH + aoff[mi]);
                al[mi] = *(const bf16x8*)(AsL + aoff[mi]);
            }
            asm volatile("s_waitcnt lgkmcnt(0)" ::: "memory");
            __builtin_amdgcn_sched_barrier(0);
            __builtin_amdgcn_s_barrier();           // all A(kw) reads retired
            if (kw < 7) { stageA(kw + 1); stageB(cur ^ 1, kw + 1); }
            #pragma unroll
            for (int nj = 0; nj < 4; nj++) {
                bf16x8 bh = *(const bf16x8*)(BsH[cur] + boff[nj]);
                bf16x8 bl = *(const bf16x8*)(BsL[cur] + boff[nj]);
                #pragma unroll
                for (int mi = 0; mi < 4; mi++) {
                    acc[mi][nj] = MFMA_BF16(ah[mi], bh, acc[mi][nj], 0, 0, 0);
                    acc[mi][nj] = MFMA_BF16(al[mi], bh, acc[mi][nj], 0, 0, 0);
                    acc[mi][nj] = MFMA_BF16(ah[mi], bl, acc[mi][nj], 0, 0, 0);
                }
            }
        }
        unsigned int* qlist = qmeta + 16;
        #pragma unroll
        for (int mi = 0; mi < 4; mi++)
            #pragma unroll
            for (int nj = 0; nj < 4; nj++)
                #pragma unroll
                for (int r = 0; r < 4; r++) {
                    int rv = M0 + wr * 64 + mi * 16 + quad * 4 + r;
                    int rp = (rv >> 3) * 24 + (rv & 7);
                    int col = n0 + wc * 64 + nj * 16 + l15;
                    float v = acc[mi][nj][r];
                    Cbf[((size_t)b * CQKV + rp) * P4096 + col] = f2bf(v);
                    qplane[((size_t)b * 256 + rv) * P4096 + col] = v;
                    if (fabsf(v) < 1e-4f) {   // sparse qfix worklist (~2.5e-4 hit rate)
                        unsigned int idx = atomicAdd(qmeta, 1u);
                        if (idx < QFIX_CAP)
                            qlist[idx] = (unsigned int)(((b * 256 + rv) << 12) | col);
                    }
                }
    } else {
        // ---- k/v rows: single term; classic dbuf, counted vmcnt(4) (32K) ----
        char* As[2] = { smem, smem + 8192 };
        char* Bs[2] = { smem + 16384, smem + 24576 };
        auto stageKV = [&](int d, int kw) {
            #pragma unroll
            for (int i = 0; i < 2; i++) {
                int lo = ldsoff + i * 4096;
                size_t so = (size_t)(i * 64) * 256 + (size_t)kw * 32;
                gload16(As[d] + lo, Ah + abase + so);
                gload16(Bs[d] + lo, Bh + bbase + so);
            }
        };
        stageKV(0, 0);
        for (int kw = 0; kw < 8; kw++) {
            int cur = kw & 1;
            if (kw < 7) {
                stageKV(cur ^ 1, kw + 1);
                asm volatile("s_waitcnt vmcnt(4)" ::: "memory");
            } else {
                asm volatile("s_waitcnt vmcnt(0)" ::: "memory");
            }
            __builtin_amdgcn_s_barrier();
            bf16x8 ah[4];
            #pragma unroll
            for (int mi = 0; mi < 4; mi++)
                ah[mi] = *(const bf16x8*)(As[cur] + aoff[mi]);
            #pragma unroll
            for (int nj = 0; nj < 4; nj++) {
                bf16x8 bh = *(const bf16x8*)(Bs[cur] + boff[nj]);
                #pragma unroll
                for (int mi = 0; mi < 4; mi++)
                    acc[mi][nj] = MFMA_BF16(ah[mi], bh, acc[mi][nj], 0, 0, 0);
            }
            __builtin_amdgcn_s_barrier();
        }
        #pragma unroll
        for (int mi = 0; mi < 4; mi++)
            #pragma unroll
            for (int nj = 0; nj < 4; nj++)
                #pragma unroll
                for (int r = 0; r < 4; r++) {
                    int rv2 = (M0 - 256) + wr * 64 + mi * 16 + quad * 4 + r;
                    int rp = (rv2 >> 4) * 24 + 8 + (rv2 & 15);
                    int col = n0 + wc * 64 + nj * 16 + l15;
                    Cbf[((size_t)b * CQKV + rp) * P4096 + col] = f2bf(acc[mi][nj][r]);
                }
    }
}

// ---------------- qfix2: sparse fp64 recompute, one wave per worklist entry ----------------
__global__ __launch_bounds__(256) void qfix2_kernel(
    float* __restrict__ qplane, const float* __restrict__ w_qkv,
    const float* __restrict__ x, const unsigned int* __restrict__ qmeta)
{
    unsigned int n = qmeta[0];
    if (n > QFIX_CAP) n = QFIX_CAP;
    const unsigned int* list = qmeta + 16;
    const int wave = threadIdx.x >> 6, lane = threadIdx.x & 63;
    for (unsigned int e = blockIdx.x * 4 + wave; e < n; e += gridDim.x * 4) {
        unsigned int i = list[e];
        int p   = (int)(i & 4095);
        int qch = (int)((i >> 12) & 255);
        int b   = (int)(i >> 20);
        int row = (qch >> 3) * 24 + (qch & 7);
        const float* wr = w_qkv + (size_t)row * 256;
        const float* xr = x + (size_t)b * 256 * P4096 + p;
        double s = 0.0;
        #pragma unroll
        for (int j = 0; j < 4; j++) {
            int c = lane * 4 + j;
            s += (double)wr[c] * (double)xr[(size_t)c * P4096];
        }
        #pragma unroll
        for (int off = 32; off > 0; off >>= 1) s += __shfl_xor(s, off, 64);
        if (lane == 0)
            qplane[((size_t)(b * 256 + qch)) * P4096 + p] = (float)s;
    }
}

// ---------------- dw 3x3 + grouped pw (bf16; feeds only heads 32-63) ----------------
__global__ __launch_bounds__(512, 8) void dwpw_kernel(
    const ushort* __restrict__ qkv, const float* __restrict__ wdw,
    const float* __restrict__ wpw, ushort* __restrict__ agg)
{
    const int rt = blockIdx.x;    // 0..3 (16 output rows each)
    const int g  = blockIdx.y;    // 0..95
    const int b  = blockIdx.z;
    const int t  = threadIdx.x;   // 0..511
    const int r0 = rt * 16;
    const int cg = g * 8;

    __shared__ __align__(16) ushort tile[8][18][80];   // 23040 B

    const ushort* src = qkv + ((size_t)(b * CQKV + cg)) * P4096;

    if (t < 288) {
        int ch = t / 36;
        int rr = (t % 36) >> 1;
        int side = t & 1;
        *(uint4*)&tile[ch][rr][side * 72] = make_uint4(0, 0, 0, 0);
    }
    #pragma unroll
    for (int i = 0; i < 3; i++) {
        int id = t + i * 512;
        if (id < 1152) {
            int ch  = id / 144;
            int rem = id - ch * 144;
            int rr  = rem >> 3;
            int oct = (rem & 7) * 8;
            int grow = r0 - 1 + rr;
            uint4 v = make_uint4(0, 0, 0, 0);
            if (grow >= 0 && grow < 64)
                v = *(const uint4*)(src + (size_t)ch * P4096 + (size_t)grow * 64 + oct);
            *(uint4*)&tile[ch][rr][8 + oct] = v;
        }
    }
    __syncthreads();

    const int kc  = t & 31;        // col pair: cols 2kc, 2kc+1
    const int row = t >> 5;        // 0..15
    const float* wdwg = wdw + (size_t)cg * 9;   // block-uniform -> s_load
    const float* wpwg = wpw + (size_t)cg * 8;

    float acc0[8], acc1[8];
    #pragma unroll
    for (int oi = 0; oi < 8; oi++) { acc0[oi] = 0.0f; acc1[oi] = 0.0f; }

    #pragma unroll
    for (int c = 0; c < 8; c++) {
        float dv0 = 0.0f, dv1 = 0.0f;
        #pragma unroll
        for (int dy = 0; dy < 3; dy++) {
            const ushort* rp = &tile[c][row + dy][2 * kc + 4];
            unsigned int u1 = *(const unsigned int*)(rp + 2);
            unsigned int u2 = *(const unsigned int*)(rp + 4);
            unsigned int u3 = *(const unsigned int*)(rp + 6);
            float xm1 = __uint_as_float(u1 & 0xffff0000u);
            float x0  = __uint_as_float(u2 << 16);
            float x1  = __uint_as_float(u2 & 0xffff0000u);
            float x2  = __uint_as_float(u3 << 16);
            float w0 = wdwg[c * 9 + dy * 3 + 0];
            float w1 = wdwg[c * 9 + dy * 3 + 1];
            float w2 = wdwg[c * 9 + dy * 3 + 2];
            dv0 = fmaf(w0, xm1, dv0); dv0 = fmaf(w1, x0, dv0); dv0 = fmaf(w2, x1, dv0);
            dv1 = fmaf(w0, x0,  dv1); dv1 = fmaf(w1, x1, dv1); dv1 = fmaf(w2, x2, dv1);
        }
        #pragma unroll
        for (int oi = 0; oi < 8; oi++) {
            float w = wpwg[oi * 8 + c];
            acc0[oi] = fmaf(w, dv0, acc0[oi]);
            acc1[oi] = fmaf(w, dv1, acc1[oi]);
        }
    }

    size_t obase = ((size_t)(b * CQKV + cg)) * P4096 + (size_t)(r0 + row) * 64 + 2 * kc;
    #pragma unroll
    for (int oi = 0; oi < 8; oi++) {
        unsigned int u = (unsigned int)f2bf(acc0[oi]) |
                         ((unsigned int)f2bf(acc1[oi]) << 16);
        *(unsigned int*)&agg[obase + (size_t)oi * P4096] = u;
    }
}

// ---------------- kv[b,h,d,e] = sum_p relu(k_d)*v_e  (v_8 = 1) ----------------
__global__ __launch_bounds__(256) void kv_kernel(
    const ushort* __restrict__ qkv, const ushort* __restrict__ agg,
    float* __restrict__ kv)
{
    const int h = blockIdx.x, b = blockIdx.y, t = threadIdx.x;
    const ushort* src = (h < 32)
        ? qkv + ((size_t)(b * CQKV + h * 24)) * P4096
        : agg + ((size_t)(b * CQKV + (h - 32) * 24)) * P4096;

    float acc[72];
    #pragma unroll
    for (int i = 0; i < 72; i++) acc[i] = 0.0f;

    for (int pi = 0; pi < 16; pi++) {
        int p = t + pi * 256;
        float kvv[8], vv[8];
        #pragma unroll
        for (int d = 0; d < 8; d++) {
            float xk = bf2f(src[(size_t)(8 + d) * P4096 + p]);
            kvv[d] = xk > 0.0f ? xk : 0.0f;
        }
        #pragma unroll
        for (int e = 0; e < 8; e++) vv[e] = bf2f(src[(size_t)(16 + e) * P4096 + p]);
        #pragma unroll
        for (int d = 0; d < 8; d++) {
            #pragma unroll
            for (int e = 0; e < 8; e++) acc[d * 9 + e] += kvv[d] * vv[e];
            acc[d * 9 + 8] += kvv[d];
        }
    }

    #pragma unroll
    for (int i = 0; i < 72; i++) {
        float v = acc[i];
        #pragma unroll
        for (int off = 32; off > 0; off >>= 1) v += __shfl_xor(v, off, 64);
        acc[i] = v;
    }
    __shared__ float part[4][72];
    int wave = t >> 6, lane = t & 63;
    if (lane == 0) {
        #pragma unroll
        for (int i = 0; i < 72; i++) part[wave][i] = acc[i];
    }
    __syncthreads();
    if (t < 72)
        kv[((size_t)b * 64 + h) * 72 + t] = part[0][t] + part[1][t] + part[2][t] + part[3][t];
}

// ---------------- attn: out = (q.kv)_e / ((q.kv)_8 + 1e-15), 2 px/thread ----------------
__global__ __launch_bounds__(256) void attn_out_kernel(
    const float* __restrict__ qplane, ushort* __restrict__ agg,
    const float* __restrict__ kv)
{
    const int pt = blockIdx.x, h = blockIdx.y, b = blockIdx.z, t = threadIdx.x;
    __shared__ float kvs[72];
    if (t < 72) kvs[t] = kv[((size_t)b * 64 + h) * 72 + t];
    __syncthreads();

    const bool lohead = (h < 32);
    const float* srcf = lohead
        ? qplane + ((size_t)(b * 256 + h * 8)) * P4096 : nullptr;
    const ushort* srcb = lohead ? nullptr
        : agg + ((size_t)(b * CQKV + (h - 32) * 24)) * P4096;

    int p = pt * 512 + t * 2;
    float num0[8], num1[8]; float den0 = 0.0f, den1 = 0.0f;
    #pragma unroll
    for (int e = 0; e < 8; e++) { num0[e] = 0.0f; num1[e] = 0.0f; }
    #pragma unroll
    for (int d = 0; d < 8; d++) {
        float q0, q1;
        if (lohead) {
            float2 qq = *(const float2*)(srcf + (size_t)d * P4096 + p);
            q0 = qq.x; q1 = qq.y;
        } else {
            unsigned int u = *(const unsigned int*)(srcb + (size_t)d * P4096 + p);
            q0 = bf2f((ushort)(u & 0xffff)); q1 = bf2f((ushort)(u >> 16));
        }
        q0 = q0 > 0.0f ? q0 : 0.0f;
        q1 = q1 > 0.0f ? q1 : 0.0f;
        #pragma unroll
        for (int e = 0; e < 8; e++) {
            num0[e] += q0 * kvs[d * 9 + e];
            num1[e] += q1 * kvs[d * 9 + e];
        }
        den0 += q0 * kvs[d * 9 + 8];
        den1 += q1 * kvs[d * 9 + 8];
    }
    float rd0 = 1.0f / (den0 + 1e-15f);
    float rd1 = 1.0f / (den1 + 1e-15f);
    ushort* dst = agg + ((size_t)(b * CQKV + (h / 2) * 24 + 8 + (h % 2) * 8)) * P4096 + p;
    #pragma unroll
    for (int e = 0; e < 8; e++) {
        unsigned int u = (unsigned int)f2bf(num0[e] * rd0) |
                         ((unsigned int)f2bf(num1[e] * rd1) << 16);
        *(unsigned int*)(dst + (size_t)e * P4096) = u;
    }
}

// ---------------- GEMM3 v2: y = W_proj @ out, 128x128 tile, dbuf pipeline ----------------
__global__ __launch_bounds__(256, 2) void gemm_proj(
    const ushort* __restrict__ Awp,    // 256x512 bf16 swizzled
    const ushort* __restrict__ Bagg,   // out in agg k/v slots, map(k)=(k/16)*24+8+(k%16)
    float* __restrict__ Y,
    const float* __restrict__ bn_g, const float* __restrict__ bn_b,
    const float* __restrict__ bn_m, const float* __restrict__ bn_v)
{
    const int hw = blockIdx.x;                 // 0..1023
    const int lg = (hw & 7) * 128 + (hw >> 3);
    const int mt = lg & 1;
    const int rem = lg >> 1;                   // 0..511
    const int n0 = (rem & 31) * 128;
    const int b  = rem >> 5;
    const int t  = threadIdx.x;
    const int wave = t >> 6, lane = t & 63, quad = lane >> 4, l15 = lane & 15;
    const int wr = wave >> 1, wc = wave & 1;
    const int M0 = mt * 128;

    __shared__ __align__(16) ushort As[2][4096];   // [128][32]
    __shared__ __align__(16) ushort Bs[2][5120];   // [128][40]

    int aoff[4], boff[4];
    #pragma unroll
    for (int i = 0; i < 4; i++) {
        int ra = wr * 64 + i * 16 + l15;
        aoff[i] = ra * 64 + ((quad ^ ((ra >> 1) & 3)) << 4);   // bytes
        int rb = wc * 64 + i * 16 + l15;
        boff[i] = rb * 80 + quad * 16;                          // bytes, pad-40 rows
    }

    const int arow0 = t >> 2, achk = (t & 3) * 8;
    const size_t abase = (size_t)(M0 + arow0) * 512 + achk;       // i=0
    const size_t abase1 = (size_t)(M0 + 64 + arow0) * 512 + achk; // i=1 (row+64)
    const int ldsoffA = wave * 1024;   // bytes; +4096 for i=1

    const int bn_ = t & 127, half = t >> 7;
    const size_t bchanstride = (size_t)P4096;

    f32x4 acc[4][4];
    #pragma unroll
    for (int mi = 0; mi < 4; mi++)
        #pragma unroll
        for (int nj = 0; nj < 4; nj++)
            #pragma unroll
            for (int r = 0; r < 4; r++) acc[mi][nj][r] = 0.0f;

    auto stageA = [&](int d, int kw) {
        gload16((char*)As[d] + ldsoffA,        Awp + abase  + (size_t)kw * 32);
        gload16((char*)As[d] + ldsoffA + 4096, Awp + abase1 + (size_t)kw * 32);
    };
    ushort bu[16];
    auto loadB = [&](int kw) {
        const ushort* bsrc = Bagg
            + ((size_t)b * CQKV + (size_t)(kw * 2 + half) * 24 + 8) * P4096
            + n0 + bn_;
        #pragma unroll
        for (int j = 0; j < 16; j++) bu[j] = bsrc[(size_t)j * bchanstride];
    };
    auto writeB = [&](int d) {
        union { ushort us[8]; uint4 q; } P0, P1;
        #pragma unroll
        for (int j = 0; j < 8; j++) { P0.us[j] = bu[j]; P1.us[j] = bu[8 + j]; }
        ushort* dst = &Bs[d][bn_ * 40 + half * 16];
        *(uint4*)dst = P0.q;
        *(uint4*)(dst + 8) = P1.q;
    };

    // prologue
    stageA(0, 0);
    loadB(0);
    asm volatile("s_waitcnt vmcnt(0)" ::: "memory");
    writeB(0);
    asm volatile("s_waitcnt lgkmcnt(0)" ::: "memory");
    __builtin_amdgcn_s_barrier();

    for (int kw = 0; kw < 16; kw++) {
        int cur = kw & 1;
        if (kw < 15) {
            stageA(cur ^ 1, kw + 1);
            loadB(kw + 1);
        }
        bf16x8 af[4];
        #pragma unroll
        for (int mi = 0; mi < 4; mi++)
            af[mi] = *(const bf16x8*)((const char*)As[cur] + aoff[mi]);
        #pragma unroll
        for (int nj = 0; nj < 4; nj++) {
            bf16x8 bf = *(const bf16x8*)((const char*)Bs[cur] + boff[nj]);
            #pragma unroll
            for (int mi = 0; mi < 4; mi++)
                acc[mi][nj] = MFMA_BF16(af[mi], bf, acc[mi][nj], 0, 0, 0);
        }
        __builtin_amdgcn_s_barrier();       // all reads of buf[cur] complete
        if (kw < 15) {
            asm volatile("s_waitcnt vmcnt(0)" ::: "memory");  // A(next) in LDS, B(next) regs ready
            writeB(cur ^ 1);
            asm volatile("s_waitcnt lgkmcnt(0)" ::: "memory");
        }
        __builtin_amdgcn_s_barrier();
    }

    #pragma unroll
    for (int mi = 0; mi < 4; mi++)
        #pragma unroll
        for (int nj = 0; nj < 4; nj++)
            #pragma unroll
            for (int r = 0; r < 4; r++) {
                int row = M0 + wr * 64 + mi * 16 + quad * 4 + r;
                int col = n0 + wc * 64 + nj * 16 + l15;
                float inv = bn_g[row] / sqrtf(bn_v[row] + 1e-5f);
                float v = acc[mi][nj][r] * inv + (bn_b[row] - bn_m[row] * inv);
                Y[((size_t)b * 256 + row) * P4096 + col] = v;
            }
}

// ---------------- launch ----------------
extern "C" void kernel_launch(void* const* d_in, const int* in_sizes, int n_in,
                              void* d_out, int out_size, void* d_ws, size_t ws_size,
                              hipStream_t stream) {
    const float* x      = (const float*)d_in[0];
    const float* w_qkv  = (const float*)d_in[1];
    const float* w_dw   = (const float*)d_in[2];
    const float* w_pw   = (const float*)d_in[3];
    const float* w_proj = (const float*)d_in[4];
    const float* bn_g   = (const float*)d_in[5];
    const float* bn_b   = (const float*)d_in[6];
    const float* bn_m   = (const float*)d_in[7];
    const float* bn_v   = (const float*)d_in[8];
    float* y = (float*)d_out;

    char* ws = (char*)d_ws;
    ushort* qkv_bf = (ushort*)(ws);                  // 96 MiB: bf16 768ch
    float*  qplane = (float*) (ws + 100663296);      // 64 MiB: fp32 q (heads 0-31)
    ushort* agg_bf = (ushort*)(ws + 167772160);      // 96 MiB: agg; k/v slots reused for out
    // aliases inside agg region, dead once dwpw runs:
    ushort* XTh = (ushort*)(ws + 167772160);                       // 32 MiB
    ushort* XTl = (ushort*)(ws + 167772160 + 33554432);            // 32 MiB
    ushort* Awh = (ushort*)(ws + 167772160 + 67108864);            // 384 KiB
    ushort* Awl = (ushort*)(ws + 167772160 + 67108864 + 393216);   // 384 KiB
    // alias inside qplane region, dead after attn_out:
    ushort* Awp = (ushort*)(ws + 100663296);                       // 256 KiB
    float*  kvbuf  = (float*)d_out;                  // 288 KB scratch; gemm_proj overwrites
    unsigned int* qmeta = (unsigned int*)((char*)d_out + 524288);  // cnt + 8MB worklist

    conv_w<<<dim3(768), 128, 0, stream>>>(w_qkv, Awh, Awl, qmeta);
    conv_x<<<dim3(64, 4, NB), 256, 0, stream>>>(x, XTh, XTl);

    gemm_fused<<<dim3(3072), 256, 0, stream>>>(
        Awh, Awl, XTh, XTl, qkv_bf, qplane, qmeta);

    qfix2_kernel<<<dim3(1024), 256, 0, stream>>>(qplane, w_qkv, x, qmeta);

    dwpw_kernel<<<dim3(4, 96, NB), 512, 0, stream>>>(qkv_bf, w_dw, w_pw, agg_bf);

    kv_kernel<<<dim3(64, NB), 256, 0, stream>>>(qkv_bf, agg_bf, kvbuf);

    attn_out_kernel<<<dim3(8, 64, NB), 256, 0, stream>>>(qplane, agg_bf, kvbuf);

    conv_wp<<<dim3(256), 256, 0, stream>>>(w_proj, Awp);   // qplane dead now

    gemm_proj<<<dim3(1024), 256, 0, stream>>>(
        Awp, agg_bf, y, bn_g, bn_b, bn_m, bn_v);
}

// Round 11
// 384.767 us; speedup vs baseline: 1.1975x; 1.0027x over previous
//
#include <hip/hip_runtime.h>
#include <hip/hip_bf16.h>

// LiteMSA pipeline, MI355X gfx950.
// B=16, Cin=256, Cqkv=768, H=W=64 (P=4096), heads=64 (24 ch: q8,k8,v8),
// out 512 ch -> proj 256 ch + BN. Output y fp32.
//
// v10 = v9 + kv-branch 3-stage pipeline (3x(8K+8K)=48K, vmcnt(8): each
// stage gets ~2 steps to land vs ~0.3 before) + gemm_proj 3 blocks/CU.
// q branch unchanged (48 MFMA/step self-covers latency). Numerics bitwise
// unchanged.
//
// ws (256 MiB):
//   qkv_bf [0,96M)    bf16 768ch
//   qplane [96M,160M) fp32 256ch (q of heads 0-31); REUSED after attn_out
//                     for Awp (w_proj bf16 256x512, 256KB)
//   agg_bf [160M,256M) bf16 768ch; ALIASED before dwpw by XTh/XTl/Awh/Awl
// d_out: kvbuf 288K scratch at head; qmeta (cnt + worklist) at +512K.

#define NB 16
#define CQKV 768
#define P4096 4096
#define QFIX_CAP (1u << 21)

typedef __bf16 bf16x8 __attribute__((ext_vector_type(8)));
typedef float f32x4 __attribute__((ext_vector_type(4)));

#define MFMA_BF16 __builtin_amdgcn_mfma_f32_16x16x32_bf16

__device__ __forceinline__ ushort f2bf(float f) {
    union { float f; unsigned int u; } x; x.f = f;
    unsigned int u = x.u;
    unsigned int r = (u + 0x7FFFu + ((u >> 16) & 1u)) >> 16;
    return (ushort)r;
}
__device__ __forceinline__ float bf2f(ushort u) {
    union { unsigned int u; float f; } x; x.u = ((unsigned int)u) << 16;
    return x.f;
}
__device__ __forceinline__ unsigned int pk2bf(float x, float y) {
    __hip_bfloat162 h = __float22bfloat162_rn(make_float2(x, y));  // v_cvt_pk_bf16_f32 (RNE)
    union { __hip_bfloat162 b; unsigned int u; } c; c.b = h; return c.u;
}

__device__ __forceinline__ void gload16(void* lds, const void* g) {
    __builtin_amdgcn_global_load_lds(
        (const __attribute__((address_space(1))) void*)g,
        (__attribute__((address_space(3))) void*)lds, 16, 0, 0);
}

// ---------------- conv_w: w_qkv -> virt-row-ordered, swizzled bf16 hi/lo (+ zero qmeta) ----------------
// virt rows: 0..255 q (phys=(v>>3)*24+v&7), 256..767 kv (phys=(v2>>4)*24+8+v2&15).
__global__ __launch_bounds__(128) void conv_w(
    const float* __restrict__ W, ushort* __restrict__ Ah, ushort* __restrict__ Al,
    unsigned int* __restrict__ qmeta)
{
    const int rv = blockIdx.x;     // 0..767
    const int t  = threadIdx.x;    // 0..127 -> c pair
    if (rv == 0 && t == 0) qmeta[0] = 0;
    int phys;
    if (rv < 256) phys = (rv >> 3) * 24 + (rv & 7);
    else { int r2 = rv - 256; phys = (r2 >> 4) * 24 + 8 + (r2 & 15); }
    int c = t * 2;
    float w0 = W[(size_t)phys * 256 + c];
    float w1 = W[(size_t)phys * 256 + c + 1];
    unsigned int h = pk2bf(w0, w1);
    float f0 = __uint_as_float(h << 16);
    float f1 = __uint_as_float(h & 0xffff0000u);
    unsigned int l = pk2bf(w0 - f0, w1 - f1);
    int sl = ((c >> 3) & 3) ^ ((rv >> 1) & 3);
    int idx = (c & ~31) + sl * 8 + (c & 7);
    *(unsigned int*)&Ah[(size_t)rv * 256 + idx] = h;
    *(unsigned int*)&Al[(size_t)rv * 256 + idx] = l;
}

// ---------------- conv_wp: w_proj 256x512 -> swizzled bf16 ----------------
__global__ __launch_bounds__(256) void conv_wp(
    const float* __restrict__ W, ushort* __restrict__ Awp)
{
    const int m = blockIdx.x;      // 0..255
    const int t = threadIdx.x;     // 0..255 -> c pair
    int c = t * 2;
    float w0 = W[(size_t)m * 512 + c];
    float w1 = W[(size_t)m * 512 + c + 1];
    unsigned int h = pk2bf(w0, w1);
    int sl = ((c >> 3) & 3) ^ ((m >> 1) & 3);
    int idx = (c & ~31) + sl * 8 + (c & 7);
    *(unsigned int*)&Awp[(size_t)m * 512 + idx] = h;
}

// ---------------- conv_x: x [b][256][4096] f32 -> XT hi/lo [b][4096][256] bf16, swizzled ----------------
__global__ __launch_bounds__(256) void conv_x(
    const float* __restrict__ X, ushort* __restrict__ XTh, ushort* __restrict__ XTl)
{
    const int pt = blockIdx.x;        // 0..63
    const int ct = blockIdx.y;        // 0..3
    const int b  = blockIdx.z;
    const int t  = threadIdx.x;
    const int p0 = pt * 64, c0 = ct * 64;

    __shared__ float tile[64][65];

    {
        int cr = t >> 2, pc = (t & 3) * 16;
        const float* xr = X + ((size_t)b * 256 + c0 + cr) * P4096 + p0 + pc;
        float4 v0 = *(const float4*)xr;
        float4 v1 = *(const float4*)(xr + 4);
        float4 v2 = *(const float4*)(xr + 8);
        float4 v3 = *(const float4*)(xr + 12);
        float* d = &tile[cr][pc];
        d[0]=v0.x; d[1]=v0.y; d[2]=v0.z; d[3]=v0.w;
        d[4]=v1.x; d[5]=v1.y; d[6]=v1.z; d[7]=v1.w;
        d[8]=v2.x; d[9]=v2.y; d[10]=v2.z; d[11]=v2.w;
        d[12]=v3.x; d[13]=v3.y; d[14]=v3.z; d[15]=v3.w;
    }
    __syncthreads();

    #pragma unroll
    for (int pass = 0; pass < 2; pass++) {
        int tp = t >> 2;
        int cc = (t & 3) + pass * 4;      // 0..7 chunk of 8 c
        int p  = p0 + tp;
        float v[8];
        #pragma unroll
        for (int j = 0; j < 8; j++) v[j] = tile[cc * 8 + j][tp];
        union { unsigned int u[4]; uint4 q; } H, L;
        #pragma unroll
        for (int i = 0; i < 4; i++) {
            unsigned int h = pk2bf(v[2 * i], v[2 * i + 1]);
            H.u[i] = h;
            float f0 = __uint_as_float(h << 16);
            float f1 = __uint_as_float(h & 0xffff0000u);
            L.u[i] = pk2bf(v[2 * i] - f0, v[2 * i + 1] - f1);
        }
        int c = c0 + cc * 8;
        int sl = ((c >> 3) & 3) ^ ((p >> 1) & 3);
        size_t idx = ((size_t)b * P4096 + p) * 256 + (c & ~31) + sl * 8;
        *(uint4*)&XTh[idx] = H.q;
        *(uint4*)&XTl[idx] = L.q;
    }
}

// ---------------- gemm_fused: all 768 virt rows; q tiles 3-term, kv tiles 1-term ----------------
// 128x128 tile, BK=32, 4 waves (2x2), 48KB LDS -> 3 blocks/CU.
// q branch: A (L2-hot) single-buffered, B double-buffered; per step:
//   vmcnt(0); bar; read A frags; lgkmcnt(0)+schedbar; bar; stage(k+1); B+MFMA.
// kv branch: 3-STAGE pipeline (3x(8K+8K)); stage(kw+2) issued at step kw,
//   vmcnt(8) -> each stage has ~2 steps to land (covers ~900cy HBM latency).
// Grid 3072, XCD swizzle. q epilogue emits sparse qfix worklist.
__global__ __launch_bounds__(256, 3) void gemm_fused(
    const ushort* __restrict__ Ah, const ushort* __restrict__ Al,
    const ushort* __restrict__ Bh, const ushort* __restrict__ Bl,
    ushort* __restrict__ Cbf, float* __restrict__ qplane,
    unsigned int* __restrict__ qmeta)
{
    const int hw = blockIdx.x;                 // 0..3071
    const int lg = (hw & 7) * 384 + (hw >> 3); // XCD-contiguous logical id
    const int mt = lg % 6;
    const int rem = lg / 6;                    // 0..511
    const int n0 = (rem & 31) * 128;
    const int b  = rem >> 5;
    const int t  = threadIdx.x;
    const int wave = t >> 6, lane = t & 63, quad = lane >> 4, l15 = lane & 15;
    const int wr = wave >> 1, wc = wave & 1;
    const int M0 = mt * 128;

    __shared__ __align__(16) char smem[49152];   // 48 KB

    int aoff[4], boff[4];
    #pragma unroll
    for (int i = 0; i < 4; i++) {
        int ra = wr * 64 + i * 16 + l15;
        aoff[i] = ra * 64 + ((quad ^ ((ra >> 1) & 3)) << 4);
        int rb = wc * 64 + i * 16 + l15;
        boff[i] = rb * 64 + ((quad ^ ((rb >> 1) & 3)) << 4);
    }

    const int srow = t >> 2;               // 0..63
    const int schunk = (t & 3) * 8;        // ushort offset in 32-ushort window
    const size_t abase = (size_t)(M0 + srow) * 256 + schunk;
    const size_t bbase = ((size_t)b * P4096 + n0 + srow) * 256 + schunk;
    const int ldsoff = wave * 1024;        // bytes; +i*4096

    f32x4 acc[4][4];
    #pragma unroll
    for (int mi = 0; mi < 4; mi++)
        #pragma unroll
        for (int nj = 0; nj < 4; nj++)
            #pragma unroll
            for (int r = 0; r < 4; r++) acc[mi][nj][r] = 0.0f;

    if (mt < 2) {
        // ---- q rows: 3-term split; single-A (16K) + double-B (32K) ----
        char* AsH = smem;                  // 8K
        char* AsL = smem + 8192;           // 8K
        char* BsH[2] = { smem + 16384, smem + 24576 };
        char* BsL[2] = { smem + 32768, smem + 40960 };

        auto stageA = [&](int kw) {
            #pragma unroll
            for (int i = 0; i < 2; i++) {
                int lo = ldsoff + i * 4096;
                size_t so = (size_t)(i * 64) * 256 + (size_t)kw * 32;
                gload16(AsH + lo, Ah + abase + so);
                gload16(AsL + lo, Al + abase + so);
            }
        };
        auto stageB = [&](int d, int kw) {
            #pragma unroll
            for (int i = 0; i < 2; i++) {
                int lo = ldsoff + i * 4096;
                size_t so = (size_t)(i * 64) * 256 + (size_t)kw * 32;
                gload16(BsH[d] + lo, Bh + bbase + so);
                gload16(BsL[d] + lo, Bl + bbase + so);
            }
        };
        stageA(0); stageB(0, 0);
        for (int kw = 0; kw < 8; kw++) {
            int cur = kw & 1;
            asm volatile("s_waitcnt vmcnt(0)" ::: "memory");   // stage(kw) landed
            __builtin_amdgcn_s_barrier();
            bf16x8 ah[4], al[4];
            #pragma unroll
            for (int mi = 0; mi < 4; mi++) {
                ah[mi] = *(const bf16x8*)(AsH + aoff[mi]);
                al[mi] = *(const bf16x8*)(AsL + aoff[mi]);
            }
            asm volatile("s_waitcnt lgkmcnt(0)" ::: "memory");
            __builtin_amdgcn_sched_barrier(0);
            __builtin_amdgcn_s_barrier();           // all A(kw) reads retired
            if (kw < 7) { stageA(kw + 1); stageB(cur ^ 1, kw + 1); }
            #pragma unroll
            for (int nj = 0; nj < 4; nj++) {
                bf16x8 bh = *(const bf16x8*)(BsH[cur] + boff[nj]);
                bf16x8 bl = *(const bf16x8*)(BsL[cur] + boff[nj]);
                #pragma unroll
                for (int mi = 0; mi < 4; mi++) {
                    acc[mi][nj] = MFMA_BF16(ah[mi], bh, acc[mi][nj], 0, 0, 0);
                    acc[mi][nj] = MFMA_BF16(al[mi], bh, acc[mi][nj], 0, 0, 0);
                    acc[mi][nj] = MFMA_BF16(ah[mi], bl, acc[mi][nj], 0, 0, 0);
                }
            }
        }
        unsigned int* qlist = qmeta + 16;
        #pragma unroll
        for (int mi = 0; mi < 4; mi++)
            #pragma unroll
            for (int nj = 0; nj < 4; nj++)
                #pragma unroll
                for (int r = 0; r < 4; r++) {
                    int rv = M0 + wr * 64 + mi * 16 + quad * 4 + r;
                    int rp = (rv >> 3) * 24 + (rv & 7);
                    int col = n0 + wc * 64 + nj * 16 + l15;
                    float v = acc[mi][nj][r];
                    Cbf[((size_t)b * CQKV + rp) * P4096 + col] = f2bf(v);
                    qplane[((size_t)b * 256 + rv) * P4096 + col] = v;
                    if (fabsf(v) < 1e-4f) {   // sparse qfix worklist (~2.5e-4 hit rate)
                        unsigned int idx = atomicAdd(qmeta, 1u);
                        if (idx < QFIX_CAP)
                            qlist[idx] = (unsigned int)(((b * 256 + rv) << 12) | col);
                    }
                }
    } else {
        // ---- k/v rows: single term; 3-stage pipeline, vmcnt(8) ----
        char* As[3] = { smem, smem + 8192, smem + 16384 };
        char* Bs[3] = { smem + 24576, smem + 32768, smem + 40960 };
        auto stageKV = [&](int d, int kw) {
            #pragma unroll
            for (int i = 0; i < 2; i++) {
                int lo = ldsoff + i * 4096;
                size_t so = (size_t)(i * 64) * 256 + (size_t)kw * 32;
                gload16(As[d] + lo, Ah + abase + so);
                gload16(Bs[d] + lo, Bh + bbase + so);
            }
        };
        stageKV(0, 0);
        stageKV(1, 1);
        #pragma unroll
        for (int kw = 0; kw < 8; kw++) {
            int cur = kw % 3;
            if (kw < 6) {
                stageKV((kw + 2) % 3, kw + 2);
                asm volatile("s_waitcnt vmcnt(8)" ::: "memory");   // stage(kw) landed; kw+1,kw+2 in flight
            } else if (kw == 6) {
                asm volatile("s_waitcnt vmcnt(4)" ::: "memory");   // only stage(7) in flight
            } else {
                asm volatile("s_waitcnt vmcnt(0)" ::: "memory");
            }
            __builtin_amdgcn_s_barrier();
            bf16x8 ah[4];
            #pragma unroll
            for (int mi = 0; mi < 4; mi++)
                ah[mi] = *(const bf16x8*)(As[cur] + aoff[mi]);
            #pragma unroll
            for (int nj = 0; nj < 4; nj++) {
                bf16x8 bh = *(const bf16x8*)(Bs[cur] + boff[nj]);
                #pragma unroll
                for (int mi = 0; mi < 4; mi++)
                    acc[mi][nj] = MFMA_BF16(ah[mi], bh, acc[mi][nj], 0, 0, 0);
            }
            __builtin_amdgcn_s_barrier();   // reads of buf[cur] done before overwrite at kw+1
        }
        #pragma unroll
        for (int mi = 0; mi < 4; mi++)
            #pragma unroll
            for (int nj = 0; nj < 4; nj++)
                #pragma unroll
                for (int r = 0; r < 4; r++) {
                    int rv2 = (M0 - 256) + wr * 64 + mi * 16 + quad * 4 + r;
                    int rp = (rv2 >> 4) * 24 + 8 + (rv2 & 15);
                    int col = n0 + wc * 64 + nj * 16 + l15;
                    Cbf[((size_t)b * CQKV + rp) * P4096 + col] = f2bf(acc[mi][nj][r]);
                }
    }
}

// ---------------- qfix2: sparse fp64 recompute, one wave per worklist entry ----------------
__global__ __launch_bounds__(256) void qfix2_kernel(
    float* __restrict__ qplane, const float* __restrict__ w_qkv,
    const float* __restrict__ x, const unsigned int* __restrict__ qmeta)
{
    unsigned int n = qmeta[0];
    if (n > QFIX_CAP) n = QFIX_CAP;
    const unsigned int* list = qmeta + 16;
    const int wave = threadIdx.x >> 6, lane = threadIdx.x & 63;
    for (unsigned int e = blockIdx.x * 4 + wave; e < n; e += gridDim.x * 4) {
        unsigned int i = list[e];
        int p   = (int)(i & 4095);
        int qch = (int)((i >> 12) & 255);
        int b   = (int)(i >> 20);
        int row = (qch >> 3) * 24 + (qch & 7);
        const float* wr = w_qkv + (size_t)row * 256;
        const float* xr = x + (size_t)b * 256 * P4096 + p;
        double s = 0.0;
        #pragma unroll
        for (int j = 0; j < 4; j++) {
            int c = lane * 4 + j;
            s += (double)wr[c] * (double)xr[(size_t)c * P4096];
        }
        #pragma unroll
        for (int off = 32; off > 0; off >>= 1) s += __shfl_xor(s, off, 64);
        if (lane == 0)
            qplane[((size_t)(b * 256 + qch)) * P4096 + p] = (float)s;
    }
}

// ---------------- dw 3x3 + grouped pw (bf16; feeds only heads 32-63) ----------------
__global__ __launch_bounds__(512, 8) void dwpw_kernel(
    const ushort* __restrict__ qkv, const float* __restrict__ wdw,
    const float* __restrict__ wpw, ushort* __restrict__ agg)
{
    const int rt = blockIdx.x;    // 0..3 (16 output rows each)
    const int g  = blockIdx.y;    // 0..95
    const int b  = blockIdx.z;
    const int t  = threadIdx.x;   // 0..511
    const int r0 = rt * 16;
    const int cg = g * 8;

    __shared__ __align__(16) ushort tile[8][18][80];   // 23040 B

    const ushort* src = qkv + ((size_t)(b * CQKV + cg)) * P4096;

    if (t < 288) {
        int ch = t / 36;
        int rr = (t % 36) >> 1;
        int side = t & 1;
        *(uint4*)&tile[ch][rr][side * 72] = make_uint4(0, 0, 0, 0);
    }
    #pragma unroll
    for (int i = 0; i < 3; i++) {
        int id = t + i * 512;
        if (id < 1152) {
            int ch  = id / 144;
            int rem = id - ch * 144;
            int rr  = rem >> 3;
            int oct = (rem & 7) * 8;
            int grow = r0 - 1 + rr;
            uint4 v = make_uint4(0, 0, 0, 0);
            if (grow >= 0 && grow < 64)
                v = *(const uint4*)(src + (size_t)ch * P4096 + (size_t)grow * 64 + oct);
            *(uint4*)&tile[ch][rr][8 + oct] = v;
        }
    }
    __syncthreads();

    const int kc  = t & 31;        // col pair: cols 2kc, 2kc+1
    const int row = t >> 5;        // 0..15
    const float* wdwg = wdw + (size_t)cg * 9;   // block-uniform -> s_load
    const float* wpwg = wpw + (size_t)cg * 8;

    float acc0[8], acc1[8];
    #pragma unroll
    for (int oi = 0; oi < 8; oi++) { acc0[oi] = 0.0f; acc1[oi] = 0.0f; }

    #pragma unroll
    for (int c = 0; c < 8; c++) {
        float dv0 = 0.0f, dv1 = 0.0f;
        #pragma unroll
        for (int dy = 0; dy < 3; dy++) {
            const ushort* rp = &tile[c][row + dy][2 * kc + 4];
            unsigned int u1 = *(const unsigned int*)(rp + 2);
            unsigned int u2 = *(const unsigned int*)(rp + 4);
            unsigned int u3 = *(const unsigned int*)(rp + 6);
            float xm1 = __uint_as_float(u1 & 0xffff0000u);
            float x0  = __uint_as_float(u2 << 16);
            float x1  = __uint_as_float(u2 & 0xffff0000u);
            float x2  = __uint_as_float(u3 << 16);
            float w0 = wdwg[c * 9 + dy * 3 + 0];
            float w1 = wdwg[c * 9 + dy * 3 + 1];
            float w2 = wdwg[c * 9 + dy * 3 + 2];
            dv0 = fmaf(w0, xm1, dv0); dv0 = fmaf(w1, x0, dv0); dv0 = fmaf(w2, x1, dv0);
            dv1 = fmaf(w0, x0,  dv1); dv1 = fmaf(w1, x1, dv1); dv1 = fmaf(w2, x2, dv1);
        }
        #pragma unroll
        for (int oi = 0; oi < 8; oi++) {
            float w = wpwg[oi * 8 + c];
            acc0[oi] = fmaf(w, dv0, acc0[oi]);
            acc1[oi] = fmaf(w, dv1, acc1[oi]);
        }
    }

    size_t obase = ((size_t)(b * CQKV + cg)) * P4096 + (size_t)(r0 + row) * 64 + 2 * kc;
    #pragma unroll
    for (int oi = 0; oi < 8; oi++) {
        unsigned int u = (unsigned int)f2bf(acc0[oi]) |
                         ((unsigned int)f2bf(acc1[oi]) << 16);
        *(unsigned int*)&agg[obase + (size_t)oi * P4096] = u;
    }
}

// ---------------- kv[b,h,d,e] = sum_p relu(k_d)*v_e  (v_8 = 1) ----------------
__global__ __launch_bounds__(256) void kv_kernel(
    const ushort* __restrict__ qkv, const ushort* __restrict__ agg,
    float* __restrict__ kv)
{
    const int h = blockIdx.x, b = blockIdx.y, t = threadIdx.x;
    const ushort* src = (h < 32)
        ? qkv + ((size_t)(b * CQKV + h * 24)) * P4096
        : agg + ((size_t)(b * CQKV + (h - 32) * 24)) * P4096;

    float acc[72];
    #pragma unroll
    for (int i = 0; i < 72; i++) acc[i] = 0.0f;

    for (int pi = 0; pi < 16; pi++) {
        int p = t + pi * 256;
        float kvv[8], vv[8];
        #pragma unroll
        for (int d = 0; d < 8; d++) {
            float xk = bf2f(src[(size_t)(8 + d) * P4096 + p]);
            kvv[d] = xk > 0.0f ? xk : 0.0f;
        }
        #pragma unroll
        for (int e = 0; e < 8; e++) vv[e] = bf2f(src[(size_t)(16 + e) * P4096 + p]);
        #pragma unroll
        for (int d = 0; d < 8; d++) {
            #pragma unroll
            for (int e = 0; e < 8; e++) acc[d * 9 + e] += kvv[d] * vv[e];
            acc[d * 9 + 8] += kvv[d];
        }
    }

    #pragma unroll
    for (int i = 0; i < 72; i++) {
        float v = acc[i];
        #pragma unroll
        for (int off = 32; off > 0; off >>= 1) v += __shfl_xor(v, off, 64);
        acc[i] = v;
    }
    __shared__ float part[4][72];
    int wave = t >> 6, lane = t & 63;
    if (lane == 0) {
        #pragma unroll
        for (int i = 0; i < 72; i++) part[wave][i] = acc[i];
    }
    __syncthreads();
    if (t < 72)
        kv[((size_t)b * 64 + h) * 72 + t] = part[0][t] + part[1][t] + part[2][t] + part[3][t];
}

// ---------------- attn: out = (q.kv)_e / ((q.kv)_8 + 1e-15), 2 px/thread ----------------
__global__ __launch_bounds__(256) void attn_out_kernel(
    const float* __restrict__ qplane, ushort* __restrict__ agg,
    const float* __restrict__ kv)
{
    const int pt = blockIdx.x, h = blockIdx.y, b = blockIdx.z, t = threadIdx.x;
    __shared__ float kvs[72];
    if (t < 72) kvs[t] = kv[((size_t)b * 64 + h) * 72 + t];
    __syncthreads();

    const bool lohead = (h < 32);
    const float* srcf = lohead
        ? qplane + ((size_t)(b * 256 + h * 8)) * P4096 : nullptr;
    const ushort* srcb = lohead ? nullptr
        : agg + ((size_t)(b * CQKV + (h - 32) * 24)) * P4096;

    int p = pt * 512 + t * 2;
    float num0[8], num1[8]; float den0 = 0.0f, den1 = 0.0f;
    #pragma unroll
    for (int e = 0; e < 8; e++) { num0[e] = 0.0f; num1[e] = 0.0f; }
    #pragma unroll
    for (int d = 0; d < 8; d++) {
        float q0, q1;
        if (lohead) {
            float2 qq = *(const float2*)(srcf + (size_t)d * P4096 + p);
            q0 = qq.x; q1 = qq.y;
        } else {
            unsigned int u = *(const unsigned int*)(srcb + (size_t)d * P4096 + p);
            q0 = bf2f((ushort)(u & 0xffff)); q1 = bf2f((ushort)(u >> 16));
        }
        q0 = q0 > 0.0f ? q0 : 0.0f;
        q1 = q1 > 0.0f ? q1 : 0.0f;
        #pragma unroll
        for (int e = 0; e < 8; e++) {
            num0[e] += q0 * kvs[d * 9 + e];
            num1[e] += q1 * kvs[d * 9 + e];
        }
        den0 += q0 * kvs[d * 9 + 8];
        den1 += q1 * kvs[d * 9 + 8];
    }
    float rd0 = 1.0f / (den0 + 1e-15f);
    float rd1 = 1.0f / (den1 + 1e-15f);
    ushort* dst = agg + ((size_t)(b * CQKV + (h / 2) * 24 + 8 + (h % 2) * 8)) * P4096 + p;
    #pragma unroll
    for (int e = 0; e < 8; e++) {
        unsigned int u = (unsigned int)f2bf(num0[e] * rd0) |
                         ((unsigned int)f2bf(num1[e] * rd1) << 16);
        *(unsigned int*)(dst + (size_t)e * P4096) = u;
    }
}

// ---------------- GEMM3 v2: y = W_proj @ out, 128x128 tile, dbuf pipeline ----------------
__global__ __launch_bounds__(256, 3) void gemm_proj(
    const ushort* __restrict__ Awp,    // 256x512 bf16 swizzled
    const ushort* __restrict__ Bagg,   // out in agg k/v slots, map(k)=(k/16)*24+8+(k%16)
    float* __restrict__ Y,
    const float* __restrict__ bn_g, const float* __restrict__ bn_b,
    const float* __restrict__ bn_m, const float* __restrict__ bn_v)
{
    const int hw = blockIdx.x;                 // 0..1023
    const int lg = (hw & 7) * 128 + (hw >> 3);
    const int mt = lg & 1;
    const int rem = lg >> 1;                   // 0..511
    const int n0 = (rem & 31) * 128;
    const int b  = rem >> 5;
    const int t  = threadIdx.x;
    const int wave = t >> 6, lane = t & 63, quad = lane >> 4, l15 = lane & 15;
    const int wr = wave >> 1, wc = wave & 1;
    const int M0 = mt * 128;

    __shared__ __align__(16) ushort As[2][4096];   // [128][32]
    __shared__ __align__(16) ushort Bs[2][5120];   // [128][40]

    int aoff[4], boff[4];
    #pragma unroll
    for (int i = 0; i < 4; i++) {
        int ra = wr * 64 + i * 16 + l15;
        aoff[i] = ra * 64 + ((quad ^ ((ra >> 1) & 3)) << 4);   // bytes
        int rb = wc * 64 + i * 16 + l15;
        boff[i] = rb * 80 + quad * 16;                          // bytes, pad-40 rows
    }

    const int arow0 = t >> 2, achk = (t & 3) * 8;
    const size_t abase = (size_t)(M0 + arow0) * 512 + achk;       // i=0
    const size_t abase1 = (size_t)(M0 + 64 + arow0) * 512 + achk; // i=1 (row+64)
    const int ldsoffA = wave * 1024;   // bytes; +4096 for i=1

    const int bn_ = t & 127, half = t >> 7;
    const size_t bchanstride = (size_t)P4096;

    f32x4 acc[4][4];
    #pragma unroll
    for (int mi = 0; mi < 4; mi++)
        #pragma unroll
        for (int nj = 0; nj < 4; nj++)
            #pragma unroll
            for (int r = 0; r < 4; r++) acc[mi][nj][r] = 0.0f;

    auto stageA = [&](int d, int kw) {
        gload16((char*)As[d] + ldsoffA,        Awp + abase  + (size_t)kw * 32);
        gload16((char*)As[d] + ldsoffA + 4096, Awp + abase1 + (size_t)kw * 32);
    };
    ushort bu[16];
    auto loadB = [&](int kw) {
        const ushort* bsrc = Bagg
            + ((size_t)b * CQKV + (size_t)(kw * 2 + half) * 24 + 8) * P4096
            + n0 + bn_;
        #pragma unroll
        for (int j = 0; j < 16; j++) bu[j] = bsrc[(size_t)j * bchanstride];
    };
    auto writeB = [&](int d) {
        union { ushort us[8]; uint4 q; } P0, P1;
        #pragma unroll
        for (int j = 0; j < 8; j++) { P0.us[j] = bu[j]; P1.us[j] = bu[8 + j]; }
        ushort* dst = &Bs[d][bn_ * 40 + half * 16];
        *(uint4*)dst = P0.q;
        *(uint4*)(dst + 8) = P1.q;
    };

    // prologue
    stageA(0, 0);
    loadB(0);
    asm volatile("s_waitcnt vmcnt(0)" ::: "memory");
    writeB(0);
    asm volatile("s_waitcnt lgkmcnt(0)" ::: "memory");
    __builtin_amdgcn_s_barrier();

    for (int kw = 0; kw < 16; kw++) {
        int cur = kw & 1;
        if (kw < 15) {
            stageA(cur ^ 1, kw + 1);
            loadB(kw + 1);
        }
        bf16x8 af[4];
        #pragma unroll
        for (int mi = 0; mi < 4; mi++)
            af[mi] = *(const bf16x8*)((const char*)As[cur] + aoff[mi]);
        #pragma unroll
        for (int nj = 0; nj < 4; nj++) {
            bf16x8 bf = *(const bf16x8*)((const char*)Bs[cur] + boff[nj]);
            #pragma unroll
            for (int mi = 0; mi < 4; mi++)
                acc[mi][nj] = MFMA_BF16(af[mi], bf, acc[mi][nj], 0, 0, 0);
        }
        __builtin_amdgcn_s_barrier();       // all reads of buf[cur] complete
        if (kw < 15) {
            asm volatile("s_waitcnt vmcnt(0)" ::: "memory");  // A(next) in LDS, B(next) regs ready
            writeB(cur ^ 1);
            asm volatile("s_waitcnt lgkmcnt(0)" ::: "memory");
        }
        __builtin_amdgcn_s_barrier();
    }

    #pragma unroll
    for (int mi = 0; mi < 4; mi++)
        #pragma unroll
        for (int nj = 0; nj < 4; nj++)
            #pragma unroll
            for (int r = 0; r < 4; r++) {
                int row = M0 + wr * 64 + mi * 16 + quad * 4 + r;
                int col = n0 + wc * 64 + nj * 16 + l15;
                float inv = bn_g[row] / sqrtf(bn_v[row] + 1e-5f);
                float v = acc[mi][nj][r] * inv + (bn_b[row] - bn_m[row] * inv);
                Y[((size_t)b * 256 + row) * P4096 + col] = v;
            }
}

// ---------------- launch ----------------
extern "C" void kernel_launch(void* const* d_in, const int* in_sizes, int n_in,
                              void* d_out, int out_size, void* d_ws, size_t ws_size,
                              hipStream_t stream) {
    const float* x      = (const float*)d_in[0];
    const float* w_qkv  = (const float*)d_in[1];
    const float* w_dw   = (const float*)d_in[2];
    const float* w_pw   = (const float*)d_in[3];
    const float* w_proj = (const float*)d_in[4];
    const float* bn_g   = (const float*)d_in[5];
    const float* bn_b   = (const float*)d_in[6];
    const float* bn_m   = (const float*)d_in[7];
    const float* bn_v   = (const float*)d_in[8];
    float* y = (float*)d_out;

    char* ws = (char*)d_ws;
    ushort* qkv_bf = (ushort*)(ws);                  // 96 MiB: bf16 768ch
    float*  qplane = (float*) (ws + 100663296);      // 64 MiB: fp32 q (heads 0-31)
    ushort* agg_bf = (ushort*)(ws + 167772160);      // 96 MiB: agg; k/v slots reused for out
    // aliases inside agg region, dead once dwpw runs:
    ushort* XTh = (ushort*)(ws + 167772160);                       // 32 MiB
    ushort* XTl = (ushort*)(ws + 167772160 + 33554432);            // 32 MiB
    ushort* Awh = (ushort*)(ws + 167772160 + 67108864);            // 384 KiB
    ushort* Awl = (ushort*)(ws + 167772160 + 67108864 + 393216);   // 384 KiB
    // alias inside qplane region, dead after attn_out:
    ushort* Awp = (ushort*)(ws + 100663296);                       // 256 KiB
    float*  kvbuf  = (float*)d_out;                  // 288 KB scratch; gemm_proj overwrites
    unsigned int* qmeta = (unsigned int*)((char*)d_out + 524288);  // cnt + 8MB worklist

    conv_w<<<dim3(768), 128, 0, stream>>>(w_qkv, Awh, Awl, qmeta);
    conv_x<<<dim3(64, 4, NB), 256, 0, stream>>>(x, XTh, XTl);

    gemm_fused<<<dim3(3072), 256, 0, stream>>>(
        Awh, Awl, XTh, XTl, qkv_bf, qplane, qmeta);

    qfix2_kernel<<<dim3(1024), 256, 0, stream>>>(qplane, w_qkv, x, qmeta);

    dwpw_kernel<<<dim3(4, 96, NB), 512, 0, stream>>>(qkv_bf, w_dw, w_pw, agg_bf);

    kv_kernel<<<dim3(64, NB), 256, 0, stream>>>(qkv_bf, agg_bf, kvbuf);

    attn_out_kernel<<<dim3(8, 64, NB), 256, 0, stream>>>(qplane, agg_bf, kvbuf);

    conv_wp<<<dim3(256), 256, 0, stream>>>(w_proj, Awp);   // qplane dead now

    gemm_proj<<<dim3(1024), 256, 0, stream>>>(
        Awp, agg_bf, y, bn_g, bn_b, bn_m, bn_v);
}